// Round 9
// baseline (1202.670 us; speedup 1.0000x reference)
//
#include <hip/hip_runtime.h>
#include <hip/hip_bf16.h>

// ---------------------------------------------------------------------------
// LiveSR round 9: S=128 trunk chunk with U2 sub-chunked for up2+tail (fits ws
// since only tail consumes U2), halving trunk dispatch count and doubling
// trunk grids (2->3 resident blocks/CU). Tap loops unrolled (full for
// res/fused/tail which are LDS-occupancy-limited; x3 for conv_up to keep its
// 6 blocks/CU). Everything else = round 8 (verified-MFMA-only K=48 split).
// ---------------------------------------------------------------------------

#define NSAMP 128
#define NSUB  10
#define NBLK  8
#define P32E  (34 * 34 * 48)

typedef __attribute__((ext_vector_type(8))) short bf16x8;
typedef __attribute__((ext_vector_type(4))) short bf16x4;
typedef __attribute__((ext_vector_type(4))) float f32x4;

// zero-extended partial-K MFMA (ch32-47): both operands place ch32+4lk+j at
// k=8lk+j; padded k-slots contribute 0. Only the HW-verified shape is used.
__device__ inline f32x4 mfma_k16(bf16x4 a, bf16x8 b8, f32x4 c) {
    bf16x8 a8 = { a[0], a[1], a[2], a[3], (short)0, (short)0, (short)0, (short)0 };
    return __builtin_amdgcn_mfma_f32_16x16x32_bf16(a8, b8, c, 0, 0, 0);
}
__device__ inline bf16x8 ld_b4(const short* p) {
    bf16x4 t = *(const bf16x4*)p;
    bf16x8 r = { t[0], t[1], t[2], t[3], (short)0, (short)0, (short)0, (short)0 };
    return r;
}

__device__ inline short f2bf(float f) {
    union { float f; unsigned u; } v; v.f = f;
    unsigned r = (v.u + 0x7FFFu + ((v.u >> 16) & 1u)) >> 16;
    return (short)r;
}
__device__ inline float bf2f(short s) {
    union { unsigned u; float f; } v; v.u = ((unsigned)(unsigned short)s) << 16;
    return v.f;
}

union U16 { uint4 u; short s[8]; };

// sample->XCD-stable bijective swizzle
template<int RB>
__device__ inline void swz(int p, int S, int& s, int& rb) {
    if ((S & 7) == 0) {
        int x = p & 7, q = p >> 3;
        int sp = q / RB;
        s = x * (S >> 3) + sp;
        rb = q - sp * RB;
    } else {
        s = p / RB; rb = p - s * RB;
    }
}

// ---------------- weight / bias preprocessing -------------------------------
struct PrepDesc {
    const float* wsrc; const float* bsrc;
    int n_mat, CO_pad, CO_src, CO_real, CI_real, group;
    size_t sz_w, sz_b, wdst, bdst;
};
struct PrepTable { PrepDesc d[13]; };

__global__ __launch_bounds__(256)
void k_prep(PrepTable T, short* __restrict__ wb, float* __restrict__ bb,
            size_t wtot, size_t btot)
{
    size_t id = (size_t)blockIdx.x * 256 + threadIdx.x;
    if (id < wtot) {
        int s = 0; size_t off = id;
        while (off >= T.d[s].sz_w) { off -= T.d[s].sz_w; ++s; }
        const PrepDesc& D = T.d[s];
        int ci = (int)(off & 63);
        size_t q = off >> 6;
        int co = (int)(q % D.CO_pad);
        size_t q2 = q / D.CO_pad;
        int t = (int)(q2 % 9);
        int m = (int)(q2 / 9);
        float v = 0.f;
        if (co < D.CO_real && ci < D.CI_real) {
            int cs = (D.group >= 0) ? co * 4 + D.group : co;
            v = D.wsrc[(((size_t)m * D.CO_src + cs) * D.CI_real + ci) * 9 + t];
        }
        wb[D.wdst + off] = f2bf(v);
    } else if (id < wtot + btot) {
        size_t off = id - wtot;
        int s = 0;
        while (off >= T.d[s].sz_b) { off -= T.d[s].sz_b; ++s; }
        const PrepDesc& D = T.d[s];
        int co = (int)(off % D.CO_pad);
        int m  = (int)(off / D.CO_pad);
        float v = 0.f;
        if (co < D.CO_real) {
            int cs = (D.group >= 0) ? co * 4 + D.group : co;
            v = D.bsrc[(size_t)m * D.CO_src + cs];
        }
        bb[D.bdst + off] = v;
    }
}

// combined halo zeroing (per-buffer sample counts encoded in cum[])
struct HaloTab { short* p[5]; int Hp[5]; long ss[5]; long cum[6]; };

__global__ __launch_bounds__(256)
void k_halo_all(HaloTab H)
{
    long u = (long)blockIdx.x * 256 + threadIdx.x;
    int b = 0;
    while (b < 5 && u >= H.cum[b + 1]) ++b;
    if (b >= 5) return;
    u -= H.cum[b];
    int Hp = H.Hp[b];
    int perim = 4 * Hp - 4;
    int k = (int)(u % 6);
    long q = u / 6;
    int e = (int)(q % perim);
    int s = (int)(q / perim);
    int r, c;
    if (e < Hp)            { r = 0;       c = e; }
    else if (e < 2 * Hp)   { r = Hp - 1;  c = e - Hp; }
    else { int e2 = e - 2 * Hp; r = 1 + (e2 >> 1); c = (e2 & 1) ? Hp - 1 : 0; }
    *(uint4*)(H.p[b] + (long)s * H.ss[b] + ((long)r * Hp + c) * 48 + k * 8) =
        make_uint4(0u, 0u, 0u, 0u);
}

// input fp32 NCHW -> padded channels-last bf16 [34][34][48]
__global__ __launch_bounds__(256)
void k_incl(const float* __restrict__ in, short* __restrict__ dst, int base, int S)
{
    int idx = blockIdx.x * 256 + threadIdx.x;
    if (idx >= S * 1024) return;
    int s = idx >> 10, p = idx & 1023;
    int y = p >> 5, x = p & 31;
    const float* src = in + (size_t)(base + s) * 3072 + p;
    short* d = dst + (((long)s * 34 + (y + 1)) * 34 + (x + 1)) * 48;
    uint4 z = make_uint4(0u, 0u, 0u, 0u);
    U16 a; a.u = z;
    a.s[0] = f2bf(src[0]);
    a.s[1] = f2bf(src[1024]);
    a.s[2] = f2bf(src[2048]);
    ((uint4*)d)[0] = a.u;
#pragma unroll
    for (int k = 1; k < 6; ++k) ((uint4*)d)[k] = z;
}

// ---------------- classifier (fp32, exact) ----------------------------------
__global__ __launch_bounds__(128)
void k_cls2(const float* __restrict__ in, const float* __restrict__ w,
            const float* __restrict__ bias, float* __restrict__ feat)
{
    int bid = blockIdx.x;
    int n = bid >> 6, cg = bid & 63;
    __shared__ float wl[8 * 27];
    const float* wp = w + (size_t)(cg * 8) * 27;
    for (int i = threadIdx.x; i < 216; i += 128) wl[i] = wp[i];
    __syncthreads();

    int tx = threadIdx.x & 3;
    int y  = threadIdx.x >> 2;
    int x0 = tx * 8;
    const float* x = in + (size_t)n * 3072;

    float acc[8][8];
#pragma unroll
    for (int j = 0; j < 8; ++j) {
        float bv = bias[cg * 8 + j];
#pragma unroll
        for (int k = 0; k < 8; ++k) acc[j][k] = bv;
    }

#pragma unroll
    for (int ci = 0; ci < 3; ++ci) {
        const float* pl = x + ci * 1024;
        float r0[10], r1[10], r2[10];
        {
            const float4* v = (const float4*)(pl + y * 32 + x0);
            float4 a = v[0], b = v[1];
            r1[1]=a.x; r1[2]=a.y; r1[3]=a.z; r1[4]=a.w;
            r1[5]=b.x; r1[6]=b.y; r1[7]=b.z; r1[8]=b.w;
            r1[0] = (x0 > 0)  ? pl[y*32 + x0 - 1] : 0.f;
            r1[9] = (x0 < 24) ? pl[y*32 + x0 + 8] : 0.f;
        }
        if (y > 0) {
            const float* row = pl + (y-1) * 32;
            const float4* v = (const float4*)(row + x0);
            float4 a = v[0], b = v[1];
            r0[1]=a.x; r0[2]=a.y; r0[3]=a.z; r0[4]=a.w;
            r0[5]=b.x; r0[6]=b.y; r0[7]=b.z; r0[8]=b.w;
            r0[0] = (x0 > 0)  ? row[x0 - 1] : 0.f;
            r0[9] = (x0 < 24) ? row[x0 + 8] : 0.f;
        } else {
#pragma unroll
            for (int k = 0; k < 10; ++k) r0[k] = 0.f;
        }
        if (y < 31) {
            const float* row = pl + (y+1) * 32;
            const float4* v = (const float4*)(row + x0);
            float4 a = v[0], b = v[1];
            r2[1]=a.x; r2[2]=a.y; r2[3]=a.z; r2[4]=a.w;
            r2[5]=b.x; r2[6]=b.y; r2[7]=b.z; r2[8]=b.w;
            r2[0] = (x0 > 0)  ? row[x0 - 1] : 0.f;
            r2[9] = (x0 < 24) ? row[x0 + 8] : 0.f;
        } else {
#pragma unroll
            for (int k = 0; k < 10; ++k) r2[k] = 0.f;
        }
#pragma unroll
        for (int j = 0; j < 8; ++j) {
            const float* ww = &wl[(j * 3 + ci) * 9];
            float w0=ww[0],w1=ww[1],w2=ww[2],w3=ww[3],w4=ww[4],
                  w5=ww[5],w6=ww[6],w7=ww[7],w8=ww[8];
#pragma unroll
            for (int k = 0; k < 8; ++k)
                acc[j][k] += r0[k]*w0 + r0[k+1]*w1 + r0[k+2]*w2
                           + r1[k]*w3 + r1[k+1]*w4 + r1[k+2]*w5
                           + r2[k]*w6 + r2[k+1]*w7 + r2[k+2]*w8;
        }
    }

    float ps[8];
#pragma unroll
    for (int j = 0; j < 8; ++j) {
        float s = 0.f;
#pragma unroll
        for (int k = 0; k < 8; ++k) s += fmaxf(acc[j][k], 0.f);
        ps[j] = s;
    }
#pragma unroll
    for (int j = 0; j < 8; ++j) {
#pragma unroll
        for (int off = 32; off; off >>= 1) ps[j] += __shfl_down(ps[j], off);
    }
    __shared__ float red[2][8];
    int wv = threadIdx.x >> 6, ln = threadIdx.x & 63;
    if (ln == 0) {
#pragma unroll
        for (int j = 0; j < 8; ++j) red[wv][j] = ps[j];
    }
    __syncthreads();
    if (threadIdx.x < 8)
        feat[(size_t)n * 512 + cg * 8 + threadIdx.x] =
            (red[0][threadIdx.x] + red[1][threadIdx.x]) * (1.0f / 1024.0f);
}

__global__ __launch_bounds__(64)
void k_assign(const float* __restrict__ feat, const float* __restrict__ centers,
              int* __restrict__ assign)
{
    int n = blockIdx.x;
    int t = threadIdx.x;
    const float* f = feat + (size_t)n * 512;
    float best = -1e30f;
    int bi = 0;
    for (int k = 0; k < NSUB; ++k) {
        float s = 0.f;
        for (int d = t; d < 512; d += 64) {
            float df = f[d] - centers[(size_t)k * 512 + d];
            s += df * df;
        }
#pragma unroll
        for (int off = 32; off; off >>= 1) s += __shfl_down(s, off);
        if (t == 0) {
            float sc = 1.0f / s;
            if (sc > best) { best = sc; bi = k; }
        }
    }
    if (t == 0) assign[n] = bi;
}

// ---------------- residual-type single conv (head / body) -------------------
// EPI: 0 = store, 1 = store + skip-add, 2 = store to out and out2
template<int EPI, bool RELU>
__global__ __launch_bounds__(256)
void k_conv_res(const short* __restrict__ act, long act_ss,
                const short* __restrict__ wt, long wt_es,
                const float* __restrict__ bias, long b_es,
                const int* __restrict__ assign, int abase,
                short* __restrict__ out, long out_ss,
                const short* __restrict__ skip,
                short* __restrict__ out2, int S)
{
    constexpr int PW = 34, LROWS = 6, RB = 8;
    __shared__ __align__(16) char lds[LROWS * PW * 96 + 128 * 52 * 4];
    float* bounce = (float*)&lds[LROWS * PW * 96];

    int s, rb;
    swz<RB>(blockIdx.x, S, s, rb);
    int a = assign[abase + s];
    const short* wte = wt + (long)a * wt_es;
    const float* be  = bias + (long)a * b_es;

    {
        const short* src = act + (long)s * act_ss + (long)rb * 4 * PW * 48;
        constexpr int NCH = LROWS * PW * 6;
        for (int i = threadIdx.x; i < NCH; i += 256) {
            int pl = i / 6, c = i - pl * 6;
            int px = pl % PW;
            uint4 v = *(const uint4*)(src + (long)pl * 48 + c * 8);
            *(uint4*)(&lds[pl * 96 + ((c * 16) ^ ((px & 4) << 2))]) = v;
        }
    }
    __syncthreads();

    int lane = threadIdx.x & 63, wv = threadIdx.x >> 6;
    int lm = lane & 15, lk = lane >> 4;

    f32x4 acc[2][3];
#pragma unroll
    for (int nf = 0; nf < 3; ++nf) {
        float bb = be[nf * 16 + lm];
        f32x4 iv = { bb, bb, bb, bb };
        acc[0][nf] = iv; acc[1][nf] = iv;
    }
    int rA[2], xA[2];
#pragma unroll
    for (int q = 0; q < 2; ++q) {
        int pl = (wv * 2 + q) * 16 + lm;
        rA[q] = pl >> 5; xA[q] = pl & 31;
    }

    bf16x8 Bc8[3], Bn8[3], Bc4[3], Bn4[3];
#pragma unroll
    for (int nf = 0; nf < 3; ++nf) {
        long row = (long)(nf * 16 + lm) * 64;
        Bc8[nf] = *(const bf16x8*)(wte + row + lk * 8);
        Bc4[nf] = ld_b4(wte + row + 32 + lk * 4);
    }

#pragma unroll
    for (int t = 0; t < 9; ++t) {
        if (t < 8) {
#pragma unroll
            for (int nf = 0; nf < 3; ++nf) {
                long row = (long)((t + 1) * 48 + nf * 16 + lm) * 64;
                Bn8[nf] = *(const bf16x8*)(wte + row + lk * 8);
                Bn4[nf] = ld_b4(wte + row + 32 + lk * 4);
            }
        }
        int dy = t / 3 - 1, dx = t % 3 - 1;
#pragma unroll
        for (int q = 0; q < 2; ++q) {
            int ppx = xA[q] + 1 + dx;
            int bofs = ((rA[q] + 1 + dy) * PW + ppx) * 96;
            int sw = (ppx & 4) << 2;
            bf16x8 A0 = *(const bf16x8*)(&lds[bofs + ((lk * 16) ^ sw)]);
            bf16x4 A1 = *(const bf16x4*)(&lds[bofs + ((64 + lk * 8) ^ sw)]);
#pragma unroll
            for (int nf = 0; nf < 3; ++nf) {
                acc[q][nf] = __builtin_amdgcn_mfma_f32_16x16x32_bf16(A0, Bc8[nf], acc[q][nf], 0, 0, 0);
                acc[q][nf] = mfma_k16(A1, Bc4[nf], acc[q][nf]);
            }
        }
#pragma unroll
        for (int nf = 0; nf < 3; ++nf) {
            Bc8[nf] = Bn8[nf]; Bc4[nf] = Bn4[nf];
        }
    }

#pragma unroll
    for (int q = 0; q < 2; ++q)
#pragma unroll
        for (int nf = 0; nf < 3; ++nf)
#pragma unroll
            for (int rg = 0; rg < 4; ++rg) {
                int pe = (wv * 2 + q) * 16 + lk * 4 + rg;
                float v = acc[q][nf][rg];
                if (RELU) v = fmaxf(v, 0.f);
                bounce[pe * 52 + nf * 16 + lm] = v;
            }
    __syncthreads();

    for (int u = threadIdx.x; u < 768; u += 256) {
        int px = u / 6, k = u - px * 6;
        int r = px >> 5, x = px & 31;
        long off = (long)s * out_ss + ((long)(rb * 4 + r + 1) * PW + (x + 1)) * 48 + k * 8;
        f32x4 v0 = *(f32x4*)&bounce[px * 52 + k * 8];
        f32x4 v1 = *(f32x4*)&bounce[px * 52 + k * 8 + 4];
        if (EPI == 1) {
            U16 sk; sk.u = *(const uint4*)(skip + off);
            v0.x += bf2f(sk.s[0]); v0.y += bf2f(sk.s[1]);
            v0.z += bf2f(sk.s[2]); v0.w += bf2f(sk.s[3]);
            v1.x += bf2f(sk.s[4]); v1.y += bf2f(sk.s[5]);
            v1.z += bf2f(sk.s[6]); v1.w += bf2f(sk.s[7]);
        }
        U16 o;
        o.s[0] = f2bf(v0.x); o.s[1] = f2bf(v0.y); o.s[2] = f2bf(v0.z); o.s[3] = f2bf(v0.w);
        o.s[4] = f2bf(v1.x); o.s[5] = f2bf(v1.y); o.s[6] = f2bf(v1.z); o.s[7] = f2bf(v1.w);
        *(uint4*)(out + off) = o.u;
        if (EPI == 2) *(uint4*)(out2 + off) = o.u;
    }
}

// ---------------- fused residual block: out = in + conv2(relu(conv1(in))) ---
__global__ __launch_bounds__(256)
void k_res_fused(const short* __restrict__ in, short* __restrict__ outb,
                 const short* __restrict__ wt1, const float* __restrict__ b1,
                 const short* __restrict__ wt2, const float* __restrict__ b2,
                 long wt_es, long b_es,
                 const int* __restrict__ assign, int abase, int S)
{
    constexpr int PW = 34;
    __shared__ __align__(16) char bst[8 * PW * 96];   // b padded rows R0-1..R0+6
    __shared__ __align__(16) char tst[25600];         // t (6*PW*96=19584) / bounce alias
    float* bounce = (float*)tst;

    int s, rb;
    swz<8>(blockIdx.x, S, s, rb);
    int a = assign[abase + s];
    const short* w1 = wt1 + (long)a * wt_es;
    const short* w2 = wt2 + (long)a * wt_es;
    const float* bb1 = b1 + (long)a * b_es;
    const float* bb2 = b2 + (long)a * b_es;
    int R0 = rb * 4;
    uint4 z = make_uint4(0u, 0u, 0u, 0u);

    // zero t region (col halos + boundary rows must be zero)
    for (int i = threadIdx.x; i < 6 * PW * 6; i += 256)
        *(uint4*)(&tst[i * 16]) = z;
    // stage b: padded rows R0-1 .. R0+6
    {
        const short* src = in + (long)s * P32E;
        for (int i = threadIdx.x; i < 8 * PW * 6; i += 256) {
            int pl = i / 6, c = i - pl * 6;
            int lr = pl / PW, pc = pl - lr * PW;
            int pr = R0 - 1 + lr;
            uint4 v = z;
            if (pr >= 0 && pr <= 33)
                v = *(const uint4*)(src + ((long)pr * PW + pc) * 48 + c * 8);
            *(uint4*)(&bst[pl * 96 + ((c * 16) ^ ((pc & 4) << 2))]) = v;
        }
    }
    __syncthreads();

    int lane = threadIdx.x & 63, wv = threadIdx.x >> 6;
    int lm = lane & 15, lk = lane >> 4;

    // ================= conv1: t rows R0-1 .. R0+4 (relu) =================
    {
        int tiv[3], xhv[3];
#pragma unroll
        for (int j = 0; j < 3; ++j) {
            int m = wv * 3 + j;
            tiv[j] = m >> 1; xhv[j] = m & 1;
        }
        f32x4 acc[3][3];
#pragma unroll
        for (int nf = 0; nf < 3; ++nf) {
            float bv = bb1[nf * 16 + lm];
            f32x4 iv = { bv, bv, bv, bv };
#pragma unroll
            for (int j = 0; j < 3; ++j) acc[j][nf] = iv;
        }

        bf16x8 Bc8[3], Bn8[3], Bc4[3], Bn4[3];
#pragma unroll
        for (int nf = 0; nf < 3; ++nf) {
            long row = (long)(nf * 16 + lm) * 64;
            Bc8[nf] = *(const bf16x8*)(w1 + row + lk * 8);
            Bc4[nf] = ld_b4(w1 + row + 32 + lk * 4);
        }

#pragma unroll
        for (int t = 0; t < 9; ++t) {
            if (t < 8) {
#pragma unroll
                for (int nf = 0; nf < 3; ++nf) {
                    long row = (long)((t + 1) * 48 + nf * 16 + lm) * 64;
                    Bn8[nf] = *(const bf16x8*)(w1 + row + lk * 8);
                    Bn4[nf] = ld_b4(w1 + row + 32 + lk * 4);
                }
            }
            int dy = t / 3, dx = t % 3 - 1;
#pragma unroll
            for (int j = 0; j < 3; ++j) {
                int pcol = xhv[j] * 16 + lm + 1 + dx;
                int bofs = ((tiv[j] + dy) * PW + pcol) * 96;
                int sw = (pcol & 4) << 2;
                bf16x8 A0 = *(const bf16x8*)(&bst[bofs + ((lk * 16) ^ sw)]);
                bf16x4 A1 = *(const bf16x4*)(&bst[bofs + ((64 + lk * 8) ^ sw)]);
#pragma unroll
                for (int nf = 0; nf < 3; ++nf) {
                    acc[j][nf] = __builtin_amdgcn_mfma_f32_16x16x32_bf16(A0, Bc8[nf], acc[j][nf], 0, 0, 0);
                    acc[j][nf] = mfma_k16(A1, Bc4[nf], acc[j][nf]);
                }
            }
#pragma unroll
            for (int nf = 0; nf < 3; ++nf) {
                Bc8[nf] = Bn8[nf]; Bc4[nf] = Bn4[nf];
            }
        }

        // write t (relu) into t stage; rows outside [0,31] stay zero
#pragma unroll
        for (int j = 0; j < 3; ++j) {
            int tr = R0 - 1 + tiv[j];
            if (tr < 0 || tr > 31) continue;
#pragma unroll
            for (int nf = 0; nf < 3; ++nf) {
                int chb = 2 * (nf * 16 + lm);
#pragma unroll
                for (int rg = 0; rg < 4; ++rg) {
                    int pc = xhv[j] * 16 + lk * 4 + rg + 1;
                    float v = fmaxf(acc[j][nf][rg], 0.f);
                    *(short*)(&tst[(tiv[j] * PW + pc) * 96 + (chb ^ ((pc & 4) << 2))]) = f2bf(v);
                }
            }
        }
    }
    __syncthreads();

    // ================= conv2 + skip: out rows R0 .. R0+3 =================
    f32x4 accout[2][3];
    {
        f32x4 acc[2][3];
#pragma unroll
        for (int nf = 0; nf < 3; ++nf) {
            float bv = bb2[nf * 16 + lm];
            f32x4 iv = { bv, bv, bv, bv };
            acc[0][nf] = iv; acc[1][nf] = iv;
        }

        bf16x8 Bc8[3], Bn8[3], Bc4[3], Bn4[3];
#pragma unroll
        for (int nf = 0; nf < 3; ++nf) {
            long row = (long)(nf * 16 + lm) * 64;
            Bc8[nf] = *(const bf16x8*)(w2 + row + lk * 8);
            Bc4[nf] = ld_b4(w2 + row + 32 + lk * 4);
        }

#pragma unroll
        for (int t = 0; t < 9; ++t) {
            if (t < 8) {
#pragma unroll
                for (int nf = 0; nf < 3; ++nf) {
                    long row = (long)((t + 1) * 48 + nf * 16 + lm) * 64;
                    Bn8[nf] = *(const bf16x8*)(w2 + row + lk * 8);
                    Bn4[nf] = ld_b4(w2 + row + 32 + lk * 4);
                }
            }
            int dy = t / 3, dx = t % 3 - 1;
#pragma unroll
            for (int xh = 0; xh < 2; ++xh) {
                int pcol = xh * 16 + lm + 1 + dx;
                int bofs = ((wv + dy) * PW + pcol) * 96;
                int sw = (pcol & 4) << 2;
                bf16x8 A0 = *(const bf16x8*)(&tst[bofs + ((lk * 16) ^ sw)]);
                bf16x4 A1 = *(const bf16x4*)(&tst[bofs + ((64 + lk * 8) ^ sw)]);
#pragma unroll
                for (int nf = 0; nf < 3; ++nf) {
                    acc[xh][nf] = __builtin_amdgcn_mfma_f32_16x16x32_bf16(A0, Bc8[nf], acc[xh][nf], 0, 0, 0);
                    acc[xh][nf] = mfma_k16(A1, Bc4[nf], acc[xh][nf]);
                }
            }
#pragma unroll
            for (int nf = 0; nf < 3; ++nf) {
                Bc8[nf] = Bn8[nf]; Bc4[nf] = Bn4[nf];
            }
        }

        // skip-add from staged b (out row R0+wv = bst row wv+2)
#pragma unroll
        for (int xh = 0; xh < 2; ++xh)
#pragma unroll
            for (int nf = 0; nf < 3; ++nf) {
                int chb = 2 * (nf * 16 + lm);
                f32x4 r = acc[xh][nf];
#pragma unroll
                for (int rg = 0; rg < 4; ++rg) {
                    int pc = xh * 16 + lk * 4 + rg + 1;
                    short sv = *(const short*)(&bst[((wv + 2) * PW + pc) * 96 + (chb ^ ((pc & 4) << 2))]);
                    r[rg] += bf2f(sv);
                }
                accout[xh][nf] = r;
            }
    }
    __syncthreads();   // all tst reads done -> safe to alias bounce

#pragma unroll
    for (int xh = 0; xh < 2; ++xh)
#pragma unroll
        for (int nf = 0; nf < 3; ++nf)
#pragma unroll
            for (int rg = 0; rg < 4; ++rg) {
                int pe = wv * 32 + xh * 16 + lk * 4 + rg;   // 0..127
                bounce[pe * 50 + nf * 16 + lm] = accout[xh][nf][rg];
            }
    __syncthreads();

    for (int u = threadIdx.x; u < 768; u += 256) {
        int px = u / 6, kk = u - px * 6;
        int oi = px >> 5, col = px & 31;
        long off = (long)s * P32E + ((long)(R0 + oi + 1) * PW + (col + 1)) * 48 + kk * 8;
        U16 o;
#pragma unroll
        for (int jj = 0; jj < 8; ++jj) o.s[jj] = f2bf(bounce[px * 50 + kk * 8 + jj]);
        *(uint4*)(outb + off) = o.u;
    }
}

// ---------------- merged 4-group up-conv (pixel shuffle fused) --------------
template<int W, int INROWS>
__global__ __launch_bounds__(256)
void k_conv_up(const short* __restrict__ act, long act_ss,
               const short* __restrict__ wt, long grp_stride, long wt_es,
               const float* __restrict__ bias, long bgrp_stride, long b_es,
               const int* __restrict__ assign, int abase,
               short* __restrict__ out, long out_ss, int S)
{
    constexpr int PW = W + 2, LROWS = INROWS + 2, RB = W / INROWS;
    constexpr int OUTR = 2 * INROWS, OUTC = 2 * W, OPW = 2 * W + 2;
    constexpr int QF = INROWS * W / 16;
    constexpr int ACT_SZ = LROWS * PW * 96;
    constexpr int BNC_SZ = 6 * OUTR * OUTC * 16;
    static_assert(OUTR * OUTC == 256, "plane size must be 256 slots");
    __shared__ __align__(16) char lds[(ACT_SZ > BNC_SZ) ? ACT_SZ : BNC_SZ];
    short* bounce = (short*)lds;   // aliased over act after MFMA

    int s, rb;
    swz<RB>(blockIdx.x, S, s, rb);
    int a = assign[abase + s];
    int wv = threadIdx.x >> 6;
    const short* wte = wt + (long)wv * grp_stride + (long)a * wt_es;
    const float* be  = bias + (long)wv * bgrp_stride + (long)a * b_es;

    {
        const short* src = act + (long)s * act_ss + (long)rb * INROWS * PW * 48;
        constexpr int NCH = LROWS * PW * 6;
        for (int i = threadIdx.x; i < NCH; i += 256) {
            int pl = i / 6, c = i - pl * 6;
            int px = pl % PW;
            uint4 v = *(const uint4*)(src + (long)pl * 48 + c * 8);
            *(uint4*)(&lds[pl * 96 + ((c * 16) ^ ((px & 4) << 2))]) = v;
        }
    }
    __syncthreads();

    int lane = threadIdx.x & 63;
    int lm = lane & 15, lk = lane >> 4;
    int dy = wv >> 1, dx2 = wv & 1;

    f32x4 acc[QF][3];
#pragma unroll
    for (int nf = 0; nf < 3; ++nf) {
        float bb = be[nf * 16 + lm];
        f32x4 iv = { bb, bb, bb, bb };
#pragma unroll
        for (int qf = 0; qf < QF; ++qf) acc[qf][nf] = iv;
    }
    int rA[QF], xA[QF];
#pragma unroll
    for (int qf = 0; qf < QF; ++qf) {
        int pl = qf * 16 + lm;
        rA[qf] = pl / W; xA[qf] = pl % W;
    }

    bf16x8 Bc8[3], Bn8[3], Bc4[3], Bn4[3];
#pragma unroll
    for (int nf = 0; nf < 3; ++nf) {
        long row = (long)(nf * 16 + lm) * 64;
        Bc8[nf] = *(const bf16x8*)(wte + row + lk * 8);
        Bc4[nf] = ld_b4(wte + row + 32 + lk * 4);
    }

#pragma unroll 3
    for (int t = 0; t < 9; ++t) {
        if (t < 8) {
#pragma unroll
            for (int nf = 0; nf < 3; ++nf) {
                long row = (long)((t + 1) * 48 + nf * 16 + lm) * 64;
                Bn8[nf] = *(const bf16x8*)(wte + row + lk * 8);
                Bn4[nf] = ld_b4(wte + row + 32 + lk * 4);
            }
        }
        int tdy = t / 3 - 1, tdx = t % 3 - 1;
#pragma unroll
        for (int qf = 0; qf < QF; ++qf) {
            int ppx = xA[qf] + 1 + tdx;
            int bofs = ((rA[qf] + 1 + tdy) * PW + ppx) * 96;
            int sw = (ppx & 4) << 2;
            bf16x8 A0 = *(const bf16x8*)(&lds[bofs + ((lk * 16) ^ sw)]);
            bf16x4 A1 = *(const bf16x4*)(&lds[bofs + ((64 + lk * 8) ^ sw)]);
#pragma unroll
            for (int nf = 0; nf < 3; ++nf) {
                acc[qf][nf] = __builtin_amdgcn_mfma_f32_16x16x32_bf16(A0, Bc8[nf], acc[qf][nf], 0, 0, 0);
                acc[qf][nf] = mfma_k16(A1, Bc4[nf], acc[qf][nf]);
            }
        }
#pragma unroll
        for (int nf = 0; nf < 3; ++nf) {
            Bc8[nf] = Bn8[nf]; Bc4[nf] = Bn4[nf];
        }
    }
    __syncthreads();   // act reads done -> alias bounce

    // XOR-permuted bounce slots (involution, conflict-free writes)
#pragma unroll
    for (int qf = 0; qf < QF; ++qf)
#pragma unroll
        for (int nf = 0; nf < 3; ++nf)
#pragma unroll
            for (int rg = 0; rg < 4; ++rg) {
                int pe = qf * 16 + lk * 4 + rg;
                int r = pe / W, x = pe % W;
                int plane = nf * 2 + (lm >> 3);
                int slot = plane * 256 + (2 * r + dy) * OUTC + 2 * x + dx2;
                int phys = slot ^ ((slot >> 3) & 7) ^ (((slot >> 8) & 1) << 2);
                bounce[phys * 8 + (lm & 7)] = f2bf(acc[qf][nf][rg]);
            }
    __syncthreads();

    for (int u = threadIdx.x; u < 6 * 256; u += 256) {
        int k = u >> 8;
        int rem = u & 255;
        int rl = rem / OUTC, col = rem - rl * OUTC;
        int phys = u ^ ((u >> 3) & 7) ^ (((u >> 8) & 1) << 2);
        long off = (long)s * out_ss + ((long)(rb * OUTR + rl + 1) * OPW + (col + 1)) * 48 + k * 8;
        *(uint4*)(out + off) = ((uint4*)bounce)[phys];
    }
}

// ---------------- tail conv (36->3 @128x128) -> fp32 NCHW -------------------
__global__ __launch_bounds__(256)
void k_conv_tail(const short* __restrict__ act, long act_ss,
                 const short* __restrict__ wt, long wt_es,
                 const float* __restrict__ bias, long b_es,
                 const int* __restrict__ assign, int abase,
                 float* __restrict__ outp, int S)
{
    constexpr int PWS = 66, LROWS = 4, RB = 128;
    __shared__ __align__(16) char lds[LROWS * PWS * 96 + 3 * 2 * 64 * 4];
    float* bounce = (float*)&lds[LROWS * PWS * 96];

    int s, rb;
    swz<RB>(blockIdx.x, S, s, rb);
    int rowb = rb >> 1, colb = rb & 1;
    int a = assign[abase + s];
    const short* wte = wt + (long)a * wt_es;
    const float* be  = bias + (long)a * b_es;

    {
        constexpr int NCH = LROWS * PWS * 6;
        for (int i = threadIdx.x; i < NCH; i += 256) {
            int pl = i / 6, c = i - pl * 6;
            int lr = pl / PWS, lc = pl - lr * PWS;
            uint4 v = *(const uint4*)(act + (long)s * act_ss +
                        ((long)(rowb * 2 + lr) * 130 + colb * 64 + lc) * 48 + c * 8);
            *(uint4*)(&lds[pl * 96 + ((c * 16) ^ ((lc & 4) << 2))]) = v;
        }
    }
    __syncthreads();

    int lane = threadIdx.x & 63, wv = threadIdx.x >> 6;
    int lm = lane & 15, lk = lane >> 4;

    f32x4 acc[2];
    {
        float bb = be[lm];
        f32x4 iv = { bb, bb, bb, bb };
        acc[0] = iv; acc[1] = iv;
    }
    int rA[2], xA[2];
#pragma unroll
    for (int q = 0; q < 2; ++q) {
        int pl = (wv * 2 + q) * 16 + lm;
        rA[q] = pl >> 6; xA[q] = pl & 63;
    }

    bf16x8 Bc8, Bn8, Bc4, Bn4;
    {
        long row = (long)lm * 64;
        Bc8 = *(const bf16x8*)(wte + row + lk * 8);
        Bc4 = ld_b4(wte + row + 32 + lk * 4);
    }

#pragma unroll
    for (int t = 0; t < 9; ++t) {
        if (t < 8) {
            long row = (long)((t + 1) * 16 + lm) * 64;
            Bn8 = *(const bf16x8*)(wte + row + lk * 8);
            Bn4 = ld_b4(wte + row + 32 + lk * 4);
        }
        int dy = t / 3 - 1, dx = t % 3 - 1;
#pragma unroll
        for (int q = 0; q < 2; ++q) {
            int ppx = xA[q] + 1 + dx;
            int bofs = ((rA[q] + 1 + dy) * PWS + ppx) * 96;
            int sw = (ppx & 4) << 2;
            bf16x8 A0 = *(const bf16x8*)(&lds[bofs + ((lk * 16) ^ sw)]);
            bf16x4 A1 = *(const bf16x4*)(&lds[bofs + ((64 + lk * 8) ^ sw)]);
            acc[q] = __builtin_amdgcn_mfma_f32_16x16x32_bf16(A0, Bc8, acc[q], 0, 0, 0);
            acc[q] = mfma_k16(A1, Bc4, acc[q]);
        }
        Bc8 = Bn8; Bc4 = Bn4;
    }

    if (lm < 3) {
#pragma unroll
        for (int q = 0; q < 2; ++q)
#pragma unroll
            for (int rg = 0; rg < 4; ++rg) {
                int pe = (wv * 2 + q) * 16 + lk * 4 + rg;
                int r = pe >> 6, x = pe & 63;
                bounce[(lm * 2 + r) * 64 + x] = acc[q][rg];
            }
    }
    __syncthreads();

    for (int u = threadIdx.x; u < 384; u += 256) {
        int c = u >> 7, r = (u >> 6) & 1, x = u & 63;
        outp[(long)s * 49152 + (long)c * 16384 + (long)(rowb * 2 + r) * 128 + colb * 64 + x] =
            bounce[(c * 2 + r) * 64 + x];
    }
}

// ---------------------------------------------------------------------------
extern "C" void kernel_launch(void* const* d_in, const int* in_sizes, int n_in,
                              void* d_out, int out_size, void* d_ws, size_t ws_size,
                              hipStream_t stream)
{
    const float* inputs  = (const float*)d_in[0];
    const float* cls_w   = (const float*)d_in[1];
    const float* cls_b   = (const float*)d_in[2];
    const float* centers = (const float*)d_in[3];
    const float* head_w  = (const float*)d_in[4];
    const float* head_b  = (const float*)d_in[5];
    const float* bw1     = (const float*)d_in[6];
    const float* bb1     = (const float*)d_in[7];
    const float* bw2     = (const float*)d_in[8];
    const float* bb2     = (const float*)d_in[9];
    const float* body_w  = (const float*)d_in[10];
    const float* body_b  = (const float*)d_in[11];
    const float* up1_w   = (const float*)d_in[12];
    const float* up1_b   = (const float*)d_in[13];
    const float* up2_w   = (const float*)d_in[14];
    const float* up2_b   = (const float*)d_in[15];
    const float* tail_w  = (const float*)d_in[16];
    const float* tail_b  = (const float*)d_in[17];
    float* out = (float*)d_out;

    char* base = (char*)d_ws;
    size_t o = 0;
    auto A = [&](size_t bytes) { size_t r = o; o = (o + bytes + 255) & ~(size_t)255; return r; };

    size_t feat_o  = A(128 * 512 * 4);
    size_t asg_o   = A(512);

    const size_t HEAD_W = (size_t)10 * 9 * 48 * 64;
    const size_t BW_W   = (size_t)80 * 9 * 48 * 64;
    const size_t BODY_W = (size_t)10 * 9 * 48 * 64;
    const size_t UP_W   = (size_t)10 * 9 * 48 * 64;
    const size_t TAIL_W = (size_t)10 * 9 * 16 * 64;

    size_t headw_o = A(HEAD_W * 2);
    size_t bw1_o   = A(BW_W * 2);
    size_t bw2_o   = A(BW_W * 2);
    size_t bodyw_o = A(BODY_W * 2);
    size_t up1w_o  = A(4 * UP_W * 2);
    size_t up2w_o  = A(4 * UP_W * 2);
    size_t tailw_o = A(TAIL_W * 2);

    size_t headb_o = A(10 * 48 * 4);
    size_t bw1b_o  = A(80 * 48 * 4);
    size_t bw2b_o  = A(80 * 48 * 4);
    size_t bodyb_o = A(10 * 48 * 4);
    size_t up1b_o  = A(4 * 10 * 48 * 4);
    size_t up2b_o  = A(4 * 10 * 48 * 4);
    size_t tailb_o = A(10 * 16 * 4);

    size_t fixed_end = o;

    const size_t P32 = (size_t)34 * 34 * 48;
    const size_t PU1 = (size_t)66 * 66 * 48;
    const size_t PU2 = (size_t)130 * 130 * 48;

    // S = trunk chunk samples; SU = up2+tail sub-chunk samples (U2 sized SU)
    int S = 1, SU = 1;
    {
        bool ok = false;
        for (int s_ = NSAMP; s_ >= 1 && !ok; s_ >>= 1)
            for (int su_ = s_; su_ >= 1; su_ >>= 1) {
                size_t need = fixed_end + (size_t)s_ * (4 * P32 + PU1) * 2
                            + (size_t)su_ * PU2 * 2;
                if (need <= ws_size) { S = s_; SU = su_; ok = true; break; }
            }
    }

    short* inclB = (short*)(base + o);
    short* bB = inclB + (size_t)S * P32;
    short* tB = bB + (size_t)S * P32;
    short* hB = tB + (size_t)S * P32;
    short* U1 = hB + (size_t)S * P32;
    short* U2 = U1 + (size_t)S * PU1;

    float* feat   = (float*)(base + feat_o);
    int*   assign = (int*)(base + asg_o);
    short* wbase  = (short*)(base + headw_o);
    float* bbase  = (float*)(base + headb_o);

    short* headwt = (short*)(base + headw_o);
    short* bw1wt  = (short*)(base + bw1_o);
    short* bw2wt  = (short*)(base + bw2_o);
    short* bodywt = (short*)(base + bodyw_o);
    short* up1wt  = (short*)(base + up1w_o);
    short* up2wt  = (short*)(base + up2w_o);
    short* tailwt = (short*)(base + tailw_o);
    float* headbb = (float*)(base + headb_o);
    float* bw1bb  = (float*)(base + bw1b_o);
    float* bw2bb  = (float*)(base + bw2b_o);
    float* bodybb = (float*)(base + bodyb_o);
    float* up1bb  = (float*)(base + up1b_o);
    float* up2bb  = (float*)(base + up2b_o);
    float* tailbb = (float*)(base + tailb_o);

    PrepTable T;
    auto setd = [&](int i, const float* ws_, const float* bs_, int nm, int cop,
                    int cosrc, int coreal, int cireal, int grp,
                    size_t wdo, size_t bdo) {
        T.d[i].wsrc = ws_; T.d[i].bsrc = bs_;
        T.d[i].n_mat = nm; T.d[i].CO_pad = cop; T.d[i].CO_src = cosrc;
        T.d[i].CO_real = coreal; T.d[i].CI_real = cireal; T.d[i].group = grp;
        T.d[i].sz_w = (size_t)nm * 9 * cop * 64;
        T.d[i].sz_b = (size_t)nm * cop;
        T.d[i].wdst = (wdo - headw_o) / 2;
        T.d[i].bdst = (bdo - headb_o) / 4;
    };
    setd(0,  head_w, head_b, 10, 48, 36, 36, 3,  -1, headw_o, headb_o);
    setd(1,  bw1,    bb1,    80, 48, 36, 36, 36, -1, bw1_o,   bw1b_o);
    setd(2,  bw2,    bb2,    80, 48, 36, 36, 36, -1, bw2_o,   bw2b_o);
    setd(3,  body_w, body_b, 10, 48, 36, 36, 36, -1, bodyw_o, bodyb_o);
    for (int g = 0; g < 4; ++g)
        setd(4 + g, up1_w, up1_b, 10, 48, 144, 36, 36, g,
             up1w_o + (size_t)g * UP_W * 2, up1b_o + (size_t)g * 480 * 4);
    for (int g = 0; g < 4; ++g)
        setd(8 + g, up2_w, up2_b, 10, 48, 144, 36, 36, g,
             up2w_o + (size_t)g * UP_W * 2, up2b_o + (size_t)g * 480 * 4);
    setd(12, tail_w, tail_b, 10, 16, 3, 3, 36, -1, tailw_o, tailb_o);

    size_t wtot = 0, btot = 0;
    for (int i = 0; i < 13; ++i) { wtot += T.d[i].sz_w; btot += T.d[i].sz_b; }

    hipLaunchKernelGGL(k_prep, dim3((unsigned)((wtot + btot + 255) / 256)), dim3(256),
                       0, stream, T, wbase, bbase, wtot, btot);

    // combined halo zeroing (U2 buffer holds SU samples)
    {
        HaloTab H;
        short* ps[5] = { inclB, bB, tB, U1, U2 };
        int    hp[5] = { 34, 34, 34, 66, 130 };
        long   ss[5] = { (long)P32, (long)P32, (long)P32, (long)PU1, (long)PU2 };
        int    ns[5] = { S, S, S, S, SU };
        H.cum[0] = 0;
        for (int i = 0; i < 5; ++i) {
            H.p[i] = ps[i]; H.Hp[i] = hp[i]; H.ss[i] = ss[i];
            H.cum[i + 1] = H.cum[i] + (long)ns[i] * (4 * hp[i] - 4) * 6;
        }
        hipLaunchKernelGGL(k_halo_all, dim3((unsigned)((H.cum[5] + 255) / 256)),
                           dim3(256), 0, stream, H);
    }

    hipLaunchKernelGGL(k_cls2, dim3(NSAMP * 64), dim3(128), 0, stream,
                       inputs, cls_w, cls_b, feat);
    hipLaunchKernelGGL(k_assign, dim3(NSAMP), dim3(64), 0, stream,
                       feat, centers, assign);

    const long WES_RES  = 8L * 9 * 48 * 64;
    const long WES_ONE  = 9L * 48 * 64;
    const long WES_TAIL = 9L * 16 * 64;

    for (int bs = 0; bs < NSAMP; bs += S) {
        hipLaunchKernelGGL(k_incl, dim3((S * 1024 + 255) / 256), dim3(256), 0, stream,
                           inputs, inclB, bs, S);
        // head -> bB and hB
        hipLaunchKernelGGL((k_conv_res<2, false>), dim3(S * 8), dim3(256), 0, stream,
                           inclB, (long)P32, headwt, WES_ONE, headbb, 48L,
                           assign, bs, bB, (long)P32, (const short*)nullptr, hB, S);
        // fused residual blocks, ping-pong bB <-> tB
        short* pin = bB;
        short* pout = tB;
        for (int i = 0; i < NBLK; ++i) {
            hipLaunchKernelGGL(k_res_fused, dim3(S * 8), dim3(256), 0, stream,
                               pin, pout,
                               bw1wt + (size_t)i * WES_ONE, bw1bb + i * 48,
                               bw2wt + (size_t)i * WES_ONE, bw2bb + i * 48,
                               WES_RES, 8L * 48, assign, bs, S);
            short* tmp = pin; pin = pout; pout = tmp;
        }
        // body + global skip -> tB (pin == bB after even number of blocks)
        hipLaunchKernelGGL((k_conv_res<1, false>), dim3(S * 8), dim3(256), 0, stream,
                           pin, (long)P32, bodywt, WES_ONE, bodybb, 48L,
                           assign, bs, tB, (long)P32, hB, (short*)nullptr, S);
        // up1 merged -> U1
        hipLaunchKernelGGL((k_conv_up<32, 2>), dim3(S * 16), dim3(256), 0, stream,
                           tB, (long)P32, up1wt, (long)UP_W, WES_ONE,
                           up1bb, 480L, 48L, assign, bs, U1, (long)PU1, S);
        // up2 + tail in SU-sized sub-chunks (U2 holds SU samples)
        for (int hb = 0; hb < S; hb += SU) {
            hipLaunchKernelGGL((k_conv_up<64, 1>), dim3(SU * 64), dim3(256), 0, stream,
                               U1 + (size_t)hb * PU1, (long)PU1, up2wt, (long)UP_W, WES_ONE,
                               up2bb, 480L, 48L, assign, bs + hb, U2, (long)PU2, SU);
            hipLaunchKernelGGL(k_conv_tail, dim3(SU * 128), dim3(256), 0, stream,
                               U2, (long)PU2, tailwt, WES_TAIL, tailbb, 16L,
                               assign, bs + hb, out + (size_t)(bs + hb) * 49152, SU);
        }
    }
}

// Round 10
// 1177.545 us; speedup vs baseline: 1.0213x; 1.0213x over previous
//
#include <hip/hip_runtime.h>
#include <hip/hip_bf16.h>

// ---------------------------------------------------------------------------
// LiveSR round 10: round 8 codegen (unroll 1 tap loops, VGPR 60/76) +
// round 9's S=128 trunk chunk with U2 sub-chunked up2+tail. Round 9's
// tap-loop unrolls reverted: they raised conv_up VGPR 60->80 (occupancy
// 40->30%) and bloated the fused trunk kernels -- net -58us.
// ---------------------------------------------------------------------------

#define NSAMP 128
#define NSUB  10
#define NBLK  8
#define P32E  (34 * 34 * 48)

typedef __attribute__((ext_vector_type(8))) short bf16x8;
typedef __attribute__((ext_vector_type(4))) short bf16x4;
typedef __attribute__((ext_vector_type(4))) float f32x4;

// zero-extended partial-K MFMA (ch32-47): both operands place ch32+4lk+j at
// k=8lk+j; padded k-slots contribute 0. Only the HW-verified shape is used.
__device__ inline f32x4 mfma_k16(bf16x4 a, bf16x8 b8, f32x4 c) {
    bf16x8 a8 = { a[0], a[1], a[2], a[3], (short)0, (short)0, (short)0, (short)0 };
    return __builtin_amdgcn_mfma_f32_16x16x32_bf16(a8, b8, c, 0, 0, 0);
}
__device__ inline bf16x8 ld_b4(const short* p) {
    bf16x4 t = *(const bf16x4*)p;
    bf16x8 r = { t[0], t[1], t[2], t[3], (short)0, (short)0, (short)0, (short)0 };
    return r;
}

__device__ inline short f2bf(float f) {
    union { float f; unsigned u; } v; v.f = f;
    unsigned r = (v.u + 0x7FFFu + ((v.u >> 16) & 1u)) >> 16;
    return (short)r;
}
__device__ inline float bf2f(short s) {
    union { unsigned u; float f; } v; v.u = ((unsigned)(unsigned short)s) << 16;
    return v.f;
}

union U16 { uint4 u; short s[8]; };

// sample->XCD-stable bijective swizzle
template<int RB>
__device__ inline void swz(int p, int S, int& s, int& rb) {
    if ((S & 7) == 0) {
        int x = p & 7, q = p >> 3;
        int sp = q / RB;
        s = x * (S >> 3) + sp;
        rb = q - sp * RB;
    } else {
        s = p / RB; rb = p - s * RB;
    }
}

// ---------------- weight / bias preprocessing -------------------------------
struct PrepDesc {
    const float* wsrc; const float* bsrc;
    int n_mat, CO_pad, CO_src, CO_real, CI_real, group;
    size_t sz_w, sz_b, wdst, bdst;
};
struct PrepTable { PrepDesc d[13]; };

__global__ __launch_bounds__(256)
void k_prep(PrepTable T, short* __restrict__ wb, float* __restrict__ bb,
            size_t wtot, size_t btot)
{
    size_t id = (size_t)blockIdx.x * 256 + threadIdx.x;
    if (id < wtot) {
        int s = 0; size_t off = id;
        while (off >= T.d[s].sz_w) { off -= T.d[s].sz_w; ++s; }
        const PrepDesc& D = T.d[s];
        int ci = (int)(off & 63);
        size_t q = off >> 6;
        int co = (int)(q % D.CO_pad);
        size_t q2 = q / D.CO_pad;
        int t = (int)(q2 % 9);
        int m = (int)(q2 / 9);
        float v = 0.f;
        if (co < D.CO_real && ci < D.CI_real) {
            int cs = (D.group >= 0) ? co * 4 + D.group : co;
            v = D.wsrc[(((size_t)m * D.CO_src + cs) * D.CI_real + ci) * 9 + t];
        }
        wb[D.wdst + off] = f2bf(v);
    } else if (id < wtot + btot) {
        size_t off = id - wtot;
        int s = 0;
        while (off >= T.d[s].sz_b) { off -= T.d[s].sz_b; ++s; }
        const PrepDesc& D = T.d[s];
        int co = (int)(off % D.CO_pad);
        int m  = (int)(off / D.CO_pad);
        float v = 0.f;
        if (co < D.CO_real) {
            int cs = (D.group >= 0) ? co * 4 + D.group : co;
            v = D.bsrc[(size_t)m * D.CO_src + cs];
        }
        bb[D.bdst + off] = v;
    }
}

// combined halo zeroing (per-buffer sample counts encoded in cum[])
struct HaloTab { short* p[5]; int Hp[5]; long ss[5]; long cum[6]; };

__global__ __launch_bounds__(256)
void k_halo_all(HaloTab H)
{
    long u = (long)blockIdx.x * 256 + threadIdx.x;
    int b = 0;
    while (b < 5 && u >= H.cum[b + 1]) ++b;
    if (b >= 5) return;
    u -= H.cum[b];
    int Hp = H.Hp[b];
    int perim = 4 * Hp - 4;
    int k = (int)(u % 6);
    long q = u / 6;
    int e = (int)(q % perim);
    int s = (int)(q / perim);
    int r, c;
    if (e < Hp)            { r = 0;       c = e; }
    else if (e < 2 * Hp)   { r = Hp - 1;  c = e - Hp; }
    else { int e2 = e - 2 * Hp; r = 1 + (e2 >> 1); c = (e2 & 1) ? Hp - 1 : 0; }
    *(uint4*)(H.p[b] + (long)s * H.ss[b] + ((long)r * Hp + c) * 48 + k * 8) =
        make_uint4(0u, 0u, 0u, 0u);
}

// input fp32 NCHW -> padded channels-last bf16 [34][34][48]
__global__ __launch_bounds__(256)
void k_incl(const float* __restrict__ in, short* __restrict__ dst, int base, int S)
{
    int idx = blockIdx.x * 256 + threadIdx.x;
    if (idx >= S * 1024) return;
    int s = idx >> 10, p = idx & 1023;
    int y = p >> 5, x = p & 31;
    const float* src = in + (size_t)(base + s) * 3072 + p;
    short* d = dst + (((long)s * 34 + (y + 1)) * 34 + (x + 1)) * 48;
    uint4 z = make_uint4(0u, 0u, 0u, 0u);
    U16 a; a.u = z;
    a.s[0] = f2bf(src[0]);
    a.s[1] = f2bf(src[1024]);
    a.s[2] = f2bf(src[2048]);
    ((uint4*)d)[0] = a.u;
#pragma unroll
    for (int k = 1; k < 6; ++k) ((uint4*)d)[k] = z;
}

// ---------------- classifier (fp32, exact) ----------------------------------
__global__ __launch_bounds__(128)
void k_cls2(const float* __restrict__ in, const float* __restrict__ w,
            const float* __restrict__ bias, float* __restrict__ feat)
{
    int bid = blockIdx.x;
    int n = bid >> 6, cg = bid & 63;
    __shared__ float wl[8 * 27];
    const float* wp = w + (size_t)(cg * 8) * 27;
    for (int i = threadIdx.x; i < 216; i += 128) wl[i] = wp[i];
    __syncthreads();

    int tx = threadIdx.x & 3;
    int y  = threadIdx.x >> 2;
    int x0 = tx * 8;
    const float* x = in + (size_t)n * 3072;

    float acc[8][8];
#pragma unroll
    for (int j = 0; j < 8; ++j) {
        float bv = bias[cg * 8 + j];
#pragma unroll
        for (int k = 0; k < 8; ++k) acc[j][k] = bv;
    }

#pragma unroll
    for (int ci = 0; ci < 3; ++ci) {
        const float* pl = x + ci * 1024;
        float r0[10], r1[10], r2[10];
        {
            const float4* v = (const float4*)(pl + y * 32 + x0);
            float4 a = v[0], b = v[1];
            r1[1]=a.x; r1[2]=a.y; r1[3]=a.z; r1[4]=a.w;
            r1[5]=b.x; r1[6]=b.y; r1[7]=b.z; r1[8]=b.w;
            r1[0] = (x0 > 0)  ? pl[y*32 + x0 - 1] : 0.f;
            r1[9] = (x0 < 24) ? pl[y*32 + x0 + 8] : 0.f;
        }
        if (y > 0) {
            const float* row = pl + (y-1) * 32;
            const float4* v = (const float4*)(row + x0);
            float4 a = v[0], b = v[1];
            r0[1]=a.x; r0[2]=a.y; r0[3]=a.z; r0[4]=a.w;
            r0[5]=b.x; r0[6]=b.y; r0[7]=b.z; r0[8]=b.w;
            r0[0] = (x0 > 0)  ? row[x0 - 1] : 0.f;
            r0[9] = (x0 < 24) ? row[x0 + 8] : 0.f;
        } else {
#pragma unroll
            for (int k = 0; k < 10; ++k) r0[k] = 0.f;
        }
        if (y < 31) {
            const float* row = pl + (y+1) * 32;
            const float4* v = (const float4*)(row + x0);
            float4 a = v[0], b = v[1];
            r2[1]=a.x; r2[2]=a.y; r2[3]=a.z; r2[4]=a.w;
            r2[5]=b.x; r2[6]=b.y; r2[7]=b.z; r2[8]=b.w;
            r2[0] = (x0 > 0)  ? row[x0 - 1] : 0.f;
            r2[9] = (x0 < 24) ? row[x0 + 8] : 0.f;
        } else {
#pragma unroll
            for (int k = 0; k < 10; ++k) r2[k] = 0.f;
        }
#pragma unroll
        for (int j = 0; j < 8; ++j) {
            const float* ww = &wl[(j * 3 + ci) * 9];
            float w0=ww[0],w1=ww[1],w2=ww[2],w3=ww[3],w4=ww[4],
                  w5=ww[5],w6=ww[6],w7=ww[7],w8=ww[8];
#pragma unroll
            for (int k = 0; k < 8; ++k)
                acc[j][k] += r0[k]*w0 + r0[k+1]*w1 + r0[k+2]*w2
                           + r1[k]*w3 + r1[k+1]*w4 + r1[k+2]*w5
                           + r2[k]*w6 + r2[k+1]*w7 + r2[k+2]*w8;
        }
    }

    float ps[8];
#pragma unroll
    for (int j = 0; j < 8; ++j) {
        float s = 0.f;
#pragma unroll
        for (int k = 0; k < 8; ++k) s += fmaxf(acc[j][k], 0.f);
        ps[j] = s;
    }
#pragma unroll
    for (int j = 0; j < 8; ++j) {
#pragma unroll
        for (int off = 32; off; off >>= 1) ps[j] += __shfl_down(ps[j], off);
    }
    __shared__ float red[2][8];
    int wv = threadIdx.x >> 6, ln = threadIdx.x & 63;
    if (ln == 0) {
#pragma unroll
        for (int j = 0; j < 8; ++j) red[wv][j] = ps[j];
    }
    __syncthreads();
    if (threadIdx.x < 8)
        feat[(size_t)n * 512 + cg * 8 + threadIdx.x] =
            (red[0][threadIdx.x] + red[1][threadIdx.x]) * (1.0f / 1024.0f);
}

__global__ __launch_bounds__(64)
void k_assign(const float* __restrict__ feat, const float* __restrict__ centers,
              int* __restrict__ assign)
{
    int n = blockIdx.x;
    int t = threadIdx.x;
    const float* f = feat + (size_t)n * 512;
    float best = -1e30f;
    int bi = 0;
    for (int k = 0; k < NSUB; ++k) {
        float s = 0.f;
        for (int d = t; d < 512; d += 64) {
            float df = f[d] - centers[(size_t)k * 512 + d];
            s += df * df;
        }
#pragma unroll
        for (int off = 32; off; off >>= 1) s += __shfl_down(s, off);
        if (t == 0) {
            float sc = 1.0f / s;
            if (sc > best) { best = sc; bi = k; }
        }
    }
    if (t == 0) assign[n] = bi;
}

// ---------------- residual-type single conv (head / body) -------------------
// EPI: 0 = store, 1 = store + skip-add, 2 = store to out and out2
template<int EPI, bool RELU>
__global__ __launch_bounds__(256)
void k_conv_res(const short* __restrict__ act, long act_ss,
                const short* __restrict__ wt, long wt_es,
                const float* __restrict__ bias, long b_es,
                const int* __restrict__ assign, int abase,
                short* __restrict__ out, long out_ss,
                const short* __restrict__ skip,
                short* __restrict__ out2, int S)
{
    constexpr int PW = 34, LROWS = 6, RB = 8;
    __shared__ __align__(16) char lds[LROWS * PW * 96 + 128 * 52 * 4];
    float* bounce = (float*)&lds[LROWS * PW * 96];

    int s, rb;
    swz<RB>(blockIdx.x, S, s, rb);
    int a = assign[abase + s];
    const short* wte = wt + (long)a * wt_es;
    const float* be  = bias + (long)a * b_es;

    {
        const short* src = act + (long)s * act_ss + (long)rb * 4 * PW * 48;
        constexpr int NCH = LROWS * PW * 6;
        for (int i = threadIdx.x; i < NCH; i += 256) {
            int pl = i / 6, c = i - pl * 6;
            int px = pl % PW;
            uint4 v = *(const uint4*)(src + (long)pl * 48 + c * 8);
            *(uint4*)(&lds[pl * 96 + ((c * 16) ^ ((px & 4) << 2))]) = v;
        }
    }
    __syncthreads();

    int lane = threadIdx.x & 63, wv = threadIdx.x >> 6;
    int lm = lane & 15, lk = lane >> 4;

    f32x4 acc[2][3];
#pragma unroll
    for (int nf = 0; nf < 3; ++nf) {
        float bb = be[nf * 16 + lm];
        f32x4 iv = { bb, bb, bb, bb };
        acc[0][nf] = iv; acc[1][nf] = iv;
    }
    int rA[2], xA[2];
#pragma unroll
    for (int q = 0; q < 2; ++q) {
        int pl = (wv * 2 + q) * 16 + lm;
        rA[q] = pl >> 5; xA[q] = pl & 31;
    }

    bf16x8 Bc8[3], Bn8[3], Bc4[3], Bn4[3];
#pragma unroll
    for (int nf = 0; nf < 3; ++nf) {
        long row = (long)(nf * 16 + lm) * 64;
        Bc8[nf] = *(const bf16x8*)(wte + row + lk * 8);
        Bc4[nf] = ld_b4(wte + row + 32 + lk * 4);
    }

#pragma unroll 1
    for (int t = 0; t < 9; ++t) {
        if (t < 8) {
#pragma unroll
            for (int nf = 0; nf < 3; ++nf) {
                long row = (long)((t + 1) * 48 + nf * 16 + lm) * 64;
                Bn8[nf] = *(const bf16x8*)(wte + row + lk * 8);
                Bn4[nf] = ld_b4(wte + row + 32 + lk * 4);
            }
        }
        int dy = t / 3 - 1, dx = t % 3 - 1;
#pragma unroll
        for (int q = 0; q < 2; ++q) {
            int ppx = xA[q] + 1 + dx;
            int bofs = ((rA[q] + 1 + dy) * PW + ppx) * 96;
            int sw = (ppx & 4) << 2;
            bf16x8 A0 = *(const bf16x8*)(&lds[bofs + ((lk * 16) ^ sw)]);
            bf16x4 A1 = *(const bf16x4*)(&lds[bofs + ((64 + lk * 8) ^ sw)]);
#pragma unroll
            for (int nf = 0; nf < 3; ++nf) {
                acc[q][nf] = __builtin_amdgcn_mfma_f32_16x16x32_bf16(A0, Bc8[nf], acc[q][nf], 0, 0, 0);
                acc[q][nf] = mfma_k16(A1, Bc4[nf], acc[q][nf]);
            }
        }
#pragma unroll
        for (int nf = 0; nf < 3; ++nf) {
            Bc8[nf] = Bn8[nf]; Bc4[nf] = Bn4[nf];
        }
    }

#pragma unroll
    for (int q = 0; q < 2; ++q)
#pragma unroll
        for (int nf = 0; nf < 3; ++nf)
#pragma unroll
            for (int rg = 0; rg < 4; ++rg) {
                int pe = (wv * 2 + q) * 16 + lk * 4 + rg;
                float v = acc[q][nf][rg];
                if (RELU) v = fmaxf(v, 0.f);
                bounce[pe * 52 + nf * 16 + lm] = v;
            }
    __syncthreads();

    for (int u = threadIdx.x; u < 768; u += 256) {
        int px = u / 6, k = u - px * 6;
        int r = px >> 5, x = px & 31;
        long off = (long)s * out_ss + ((long)(rb * 4 + r + 1) * PW + (x + 1)) * 48 + k * 8;
        f32x4 v0 = *(f32x4*)&bounce[px * 52 + k * 8];
        f32x4 v1 = *(f32x4*)&bounce[px * 52 + k * 8 + 4];
        if (EPI == 1) {
            U16 sk; sk.u = *(const uint4*)(skip + off);
            v0.x += bf2f(sk.s[0]); v0.y += bf2f(sk.s[1]);
            v0.z += bf2f(sk.s[2]); v0.w += bf2f(sk.s[3]);
            v1.x += bf2f(sk.s[4]); v1.y += bf2f(sk.s[5]);
            v1.z += bf2f(sk.s[6]); v1.w += bf2f(sk.s[7]);
        }
        U16 o;
        o.s[0] = f2bf(v0.x); o.s[1] = f2bf(v0.y); o.s[2] = f2bf(v0.z); o.s[3] = f2bf(v0.w);
        o.s[4] = f2bf(v1.x); o.s[5] = f2bf(v1.y); o.s[6] = f2bf(v1.z); o.s[7] = f2bf(v1.w);
        *(uint4*)(out + off) = o.u;
        if (EPI == 2) *(uint4*)(out2 + off) = o.u;
    }
}

// ---------------- fused residual block: out = in + conv2(relu(conv1(in))) ---
__global__ __launch_bounds__(256)
void k_res_fused(const short* __restrict__ in, short* __restrict__ outb,
                 const short* __restrict__ wt1, const float* __restrict__ b1,
                 const short* __restrict__ wt2, const float* __restrict__ b2,
                 long wt_es, long b_es,
                 const int* __restrict__ assign, int abase, int S)
{
    constexpr int PW = 34;
    __shared__ __align__(16) char bst[8 * PW * 96];   // b padded rows R0-1..R0+6
    __shared__ __align__(16) char tst[25600];         // t (6*PW*96=19584) / bounce alias
    float* bounce = (float*)tst;

    int s, rb;
    swz<8>(blockIdx.x, S, s, rb);
    int a = assign[abase + s];
    const short* w1 = wt1 + (long)a * wt_es;
    const short* w2 = wt2 + (long)a * wt_es;
    const float* bb1 = b1 + (long)a * b_es;
    const float* bb2 = b2 + (long)a * b_es;
    int R0 = rb * 4;
    uint4 z = make_uint4(0u, 0u, 0u, 0u);

    // zero t region (col halos + boundary rows must be zero)
    for (int i = threadIdx.x; i < 6 * PW * 6; i += 256)
        *(uint4*)(&tst[i * 16]) = z;
    // stage b: padded rows R0-1 .. R0+6
    {
        const short* src = in + (long)s * P32E;
        for (int i = threadIdx.x; i < 8 * PW * 6; i += 256) {
            int pl = i / 6, c = i - pl * 6;
            int lr = pl / PW, pc = pl - lr * PW;
            int pr = R0 - 1 + lr;
            uint4 v = z;
            if (pr >= 0 && pr <= 33)
                v = *(const uint4*)(src + ((long)pr * PW + pc) * 48 + c * 8);
            *(uint4*)(&bst[pl * 96 + ((c * 16) ^ ((pc & 4) << 2))]) = v;
        }
    }
    __syncthreads();

    int lane = threadIdx.x & 63, wv = threadIdx.x >> 6;
    int lm = lane & 15, lk = lane >> 4;

    // ================= conv1: t rows R0-1 .. R0+4 (relu) =================
    {
        int tiv[3], xhv[3];
#pragma unroll
        for (int j = 0; j < 3; ++j) {
            int m = wv * 3 + j;
            tiv[j] = m >> 1; xhv[j] = m & 1;
        }
        f32x4 acc[3][3];
#pragma unroll
        for (int nf = 0; nf < 3; ++nf) {
            float bv = bb1[nf * 16 + lm];
            f32x4 iv = { bv, bv, bv, bv };
#pragma unroll
            for (int j = 0; j < 3; ++j) acc[j][nf] = iv;
        }

        bf16x8 Bc8[3], Bn8[3], Bc4[3], Bn4[3];
#pragma unroll
        for (int nf = 0; nf < 3; ++nf) {
            long row = (long)(nf * 16 + lm) * 64;
            Bc8[nf] = *(const bf16x8*)(w1 + row + lk * 8);
            Bc4[nf] = ld_b4(w1 + row + 32 + lk * 4);
        }

#pragma unroll 1
        for (int t = 0; t < 9; ++t) {
            if (t < 8) {
#pragma unroll
                for (int nf = 0; nf < 3; ++nf) {
                    long row = (long)((t + 1) * 48 + nf * 16 + lm) * 64;
                    Bn8[nf] = *(const bf16x8*)(w1 + row + lk * 8);
                    Bn4[nf] = ld_b4(w1 + row + 32 + lk * 4);
                }
            }
            int dy = t / 3, dx = t % 3 - 1;
#pragma unroll
            for (int j = 0; j < 3; ++j) {
                int pcol = xhv[j] * 16 + lm + 1 + dx;
                int bofs = ((tiv[j] + dy) * PW + pcol) * 96;
                int sw = (pcol & 4) << 2;
                bf16x8 A0 = *(const bf16x8*)(&bst[bofs + ((lk * 16) ^ sw)]);
                bf16x4 A1 = *(const bf16x4*)(&bst[bofs + ((64 + lk * 8) ^ sw)]);
#pragma unroll
                for (int nf = 0; nf < 3; ++nf) {
                    acc[j][nf] = __builtin_amdgcn_mfma_f32_16x16x32_bf16(A0, Bc8[nf], acc[j][nf], 0, 0, 0);
                    acc[j][nf] = mfma_k16(A1, Bc4[nf], acc[j][nf]);
                }
            }
#pragma unroll
            for (int nf = 0; nf < 3; ++nf) {
                Bc8[nf] = Bn8[nf]; Bc4[nf] = Bn4[nf];
            }
        }

        // write t (relu) into t stage; rows outside [0,31] stay zero
#pragma unroll
        for (int j = 0; j < 3; ++j) {
            int tr = R0 - 1 + tiv[j];
            if (tr < 0 || tr > 31) continue;
#pragma unroll
            for (int nf = 0; nf < 3; ++nf) {
                int chb = 2 * (nf * 16 + lm);
#pragma unroll
                for (int rg = 0; rg < 4; ++rg) {
                    int pc = xhv[j] * 16 + lk * 4 + rg + 1;
                    float v = fmaxf(acc[j][nf][rg], 0.f);
                    *(short*)(&tst[(tiv[j] * PW + pc) * 96 + (chb ^ ((pc & 4) << 2))]) = f2bf(v);
                }
            }
        }
    }
    __syncthreads();

    // ================= conv2 + skip: out rows R0 .. R0+3 =================
    f32x4 accout[2][3];
    {
        f32x4 acc[2][3];
#pragma unroll
        for (int nf = 0; nf < 3; ++nf) {
            float bv = bb2[nf * 16 + lm];
            f32x4 iv = { bv, bv, bv, bv };
            acc[0][nf] = iv; acc[1][nf] = iv;
        }

        bf16x8 Bc8[3], Bn8[3], Bc4[3], Bn4[3];
#pragma unroll
        for (int nf = 0; nf < 3; ++nf) {
            long row = (long)(nf * 16 + lm) * 64;
            Bc8[nf] = *(const bf16x8*)(w2 + row + lk * 8);
            Bc4[nf] = ld_b4(w2 + row + 32 + lk * 4);
        }

#pragma unroll 1
        for (int t = 0; t < 9; ++t) {
            if (t < 8) {
#pragma unroll
                for (int nf = 0; nf < 3; ++nf) {
                    long row = (long)((t + 1) * 48 + nf * 16 + lm) * 64;
                    Bn8[nf] = *(const bf16x8*)(w2 + row + lk * 8);
                    Bn4[nf] = ld_b4(w2 + row + 32 + lk * 4);
                }
            }
            int dy = t / 3, dx = t % 3 - 1;
#pragma unroll
            for (int xh = 0; xh < 2; ++xh) {
                int pcol = xh * 16 + lm + 1 + dx;
                int bofs = ((wv + dy) * PW + pcol) * 96;
                int sw = (pcol & 4) << 2;
                bf16x8 A0 = *(const bf16x8*)(&tst[bofs + ((lk * 16) ^ sw)]);
                bf16x4 A1 = *(const bf16x4*)(&tst[bofs + ((64 + lk * 8) ^ sw)]);
#pragma unroll
                for (int nf = 0; nf < 3; ++nf) {
                    acc[xh][nf] = __builtin_amdgcn_mfma_f32_16x16x32_bf16(A0, Bc8[nf], acc[xh][nf], 0, 0, 0);
                    acc[xh][nf] = mfma_k16(A1, Bc4[nf], acc[xh][nf]);
                }
            }
#pragma unroll
            for (int nf = 0; nf < 3; ++nf) {
                Bc8[nf] = Bn8[nf]; Bc4[nf] = Bn4[nf];
            }
        }

        // skip-add from staged b (out row R0+wv = bst row wv+2)
#pragma unroll
        for (int xh = 0; xh < 2; ++xh)
#pragma unroll
            for (int nf = 0; nf < 3; ++nf) {
                int chb = 2 * (nf * 16 + lm);
                f32x4 r = acc[xh][nf];
#pragma unroll
                for (int rg = 0; rg < 4; ++rg) {
                    int pc = xh * 16 + lk * 4 + rg + 1;
                    short sv = *(const short*)(&bst[((wv + 2) * PW + pc) * 96 + (chb ^ ((pc & 4) << 2))]);
                    r[rg] += bf2f(sv);
                }
                accout[xh][nf] = r;
            }
    }
    __syncthreads();   // all tst reads done -> safe to alias bounce

#pragma unroll
    for (int xh = 0; xh < 2; ++xh)
#pragma unroll
        for (int nf = 0; nf < 3; ++nf)
#pragma unroll
            for (int rg = 0; rg < 4; ++rg) {
                int pe = wv * 32 + xh * 16 + lk * 4 + rg;   // 0..127
                bounce[pe * 50 + nf * 16 + lm] = accout[xh][nf][rg];
            }
    __syncthreads();

    for (int u = threadIdx.x; u < 768; u += 256) {
        int px = u / 6, kk = u - px * 6;
        int oi = px >> 5, col = px & 31;
        long off = (long)s * P32E + ((long)(R0 + oi + 1) * PW + (col + 1)) * 48 + kk * 8;
        U16 o;
#pragma unroll
        for (int jj = 0; jj < 8; ++jj) o.s[jj] = f2bf(bounce[px * 50 + kk * 8 + jj]);
        *(uint4*)(outb + off) = o.u;
    }
}

// ---------------- merged 4-group up-conv (pixel shuffle fused) --------------
template<int W, int INROWS>
__global__ __launch_bounds__(256)
void k_conv_up(const short* __restrict__ act, long act_ss,
               const short* __restrict__ wt, long grp_stride, long wt_es,
               const float* __restrict__ bias, long bgrp_stride, long b_es,
               const int* __restrict__ assign, int abase,
               short* __restrict__ out, long out_ss, int S)
{
    constexpr int PW = W + 2, LROWS = INROWS + 2, RB = W / INROWS;
    constexpr int OUTR = 2 * INROWS, OUTC = 2 * W, OPW = 2 * W + 2;
    constexpr int QF = INROWS * W / 16;
    constexpr int ACT_SZ = LROWS * PW * 96;
    constexpr int BNC_SZ = 6 * OUTR * OUTC * 16;
    static_assert(OUTR * OUTC == 256, "plane size must be 256 slots");
    __shared__ __align__(16) char lds[(ACT_SZ > BNC_SZ) ? ACT_SZ : BNC_SZ];
    short* bounce = (short*)lds;   // aliased over act after MFMA

    int s, rb;
    swz<RB>(blockIdx.x, S, s, rb);
    int a = assign[abase + s];
    int wv = threadIdx.x >> 6;
    const short* wte = wt + (long)wv * grp_stride + (long)a * wt_es;
    const float* be  = bias + (long)wv * bgrp_stride + (long)a * b_es;

    {
        const short* src = act + (long)s * act_ss + (long)rb * INROWS * PW * 48;
        constexpr int NCH = LROWS * PW * 6;
        for (int i = threadIdx.x; i < NCH; i += 256) {
            int pl = i / 6, c = i - pl * 6;
            int px = pl % PW;
            uint4 v = *(const uint4*)(src + (long)pl * 48 + c * 8);
            *(uint4*)(&lds[pl * 96 + ((c * 16) ^ ((px & 4) << 2))]) = v;
        }
    }
    __syncthreads();

    int lane = threadIdx.x & 63;
    int lm = lane & 15, lk = lane >> 4;
    int dy = wv >> 1, dx2 = wv & 1;

    f32x4 acc[QF][3];
#pragma unroll
    for (int nf = 0; nf < 3; ++nf) {
        float bb = be[nf * 16 + lm];
        f32x4 iv = { bb, bb, bb, bb };
#pragma unroll
        for (int qf = 0; qf < QF; ++qf) acc[qf][nf] = iv;
    }
    int rA[QF], xA[QF];
#pragma unroll
    for (int qf = 0; qf < QF; ++qf) {
        int pl = qf * 16 + lm;
        rA[qf] = pl / W; xA[qf] = pl % W;
    }

    bf16x8 Bc8[3], Bn8[3], Bc4[3], Bn4[3];
#pragma unroll
    for (int nf = 0; nf < 3; ++nf) {
        long row = (long)(nf * 16 + lm) * 64;
        Bc8[nf] = *(const bf16x8*)(wte + row + lk * 8);
        Bc4[nf] = ld_b4(wte + row + 32 + lk * 4);
    }

#pragma unroll 1
    for (int t = 0; t < 9; ++t) {
        if (t < 8) {
#pragma unroll
            for (int nf = 0; nf < 3; ++nf) {
                long row = (long)((t + 1) * 48 + nf * 16 + lm) * 64;
                Bn8[nf] = *(const bf16x8*)(wte + row + lk * 8);
                Bn4[nf] = ld_b4(wte + row + 32 + lk * 4);
            }
        }
        int tdy = t / 3 - 1, tdx = t % 3 - 1;
#pragma unroll
        for (int qf = 0; qf < QF; ++qf) {
            int ppx = xA[qf] + 1 + tdx;
            int bofs = ((rA[qf] + 1 + tdy) * PW + ppx) * 96;
            int sw = (ppx & 4) << 2;
            bf16x8 A0 = *(const bf16x8*)(&lds[bofs + ((lk * 16) ^ sw)]);
            bf16x4 A1 = *(const bf16x4*)(&lds[bofs + ((64 + lk * 8) ^ sw)]);
#pragma unroll
            for (int nf = 0; nf < 3; ++nf) {
                acc[qf][nf] = __builtin_amdgcn_mfma_f32_16x16x32_bf16(A0, Bc8[nf], acc[qf][nf], 0, 0, 0);
                acc[qf][nf] = mfma_k16(A1, Bc4[nf], acc[qf][nf]);
            }
        }
#pragma unroll
        for (int nf = 0; nf < 3; ++nf) {
            Bc8[nf] = Bn8[nf]; Bc4[nf] = Bn4[nf];
        }
    }
    __syncthreads();   // act reads done -> alias bounce

    // XOR-permuted bounce slots (involution, conflict-free writes)
#pragma unroll
    for (int qf = 0; qf < QF; ++qf)
#pragma unroll
        for (int nf = 0; nf < 3; ++nf)
#pragma unroll
            for (int rg = 0; rg < 4; ++rg) {
                int pe = qf * 16 + lk * 4 + rg;
                int r = pe / W, x = pe % W;
                int plane = nf * 2 + (lm >> 3);
                int slot = plane * 256 + (2 * r + dy) * OUTC + 2 * x + dx2;
                int phys = slot ^ ((slot >> 3) & 7) ^ (((slot >> 8) & 1) << 2);
                bounce[phys * 8 + (lm & 7)] = f2bf(acc[qf][nf][rg]);
            }
    __syncthreads();

    for (int u = threadIdx.x; u < 6 * 256; u += 256) {
        int k = u >> 8;
        int rem = u & 255;
        int rl = rem / OUTC, col = rem - rl * OUTC;
        int phys = u ^ ((u >> 3) & 7) ^ (((u >> 8) & 1) << 2);
        long off = (long)s * out_ss + ((long)(rb * OUTR + rl + 1) * OPW + (col + 1)) * 48 + k * 8;
        *(uint4*)(out + off) = ((uint4*)bounce)[phys];
    }
}

// ---------------- tail conv (36->3 @128x128) -> fp32 NCHW -------------------
__global__ __launch_bounds__(256)
void k_conv_tail(const short* __restrict__ act, long act_ss,
                 const short* __restrict__ wt, long wt_es,
                 const float* __restrict__ bias, long b_es,
                 const int* __restrict__ assign, int abase,
                 float* __restrict__ outp, int S)
{
    constexpr int PWS = 66, LROWS = 4, RB = 128;
    __shared__ __align__(16) char lds[LROWS * PWS * 96 + 3 * 2 * 64 * 4];
    float* bounce = (float*)&lds[LROWS * PWS * 96];

    int s, rb;
    swz<RB>(blockIdx.x, S, s, rb);
    int rowb = rb >> 1, colb = rb & 1;
    int a = assign[abase + s];
    const short* wte = wt + (long)a * wt_es;
    const float* be  = bias + (long)a * b_es;

    {
        constexpr int NCH = LROWS * PWS * 6;
        for (int i = threadIdx.x; i < NCH; i += 256) {
            int pl = i / 6, c = i - pl * 6;
            int lr = pl / PWS, lc = pl - lr * PWS;
            uint4 v = *(const uint4*)(act + (long)s * act_ss +
                        ((long)(rowb * 2 + lr) * 130 + colb * 64 + lc) * 48 + c * 8);
            *(uint4*)(&lds[pl * 96 + ((c * 16) ^ ((lc & 4) << 2))]) = v;
        }
    }
    __syncthreads();

    int lane = threadIdx.x & 63, wv = threadIdx.x >> 6;
    int lm = lane & 15, lk = lane >> 4;

    f32x4 acc[2];
    {
        float bb = be[lm];
        f32x4 iv = { bb, bb, bb, bb };
        acc[0] = iv; acc[1] = iv;
    }
    int rA[2], xA[2];
#pragma unroll
    for (int q = 0; q < 2; ++q) {
        int pl = (wv * 2 + q) * 16 + lm;
        rA[q] = pl >> 6; xA[q] = pl & 63;
    }

    bf16x8 Bc8, Bn8, Bc4, Bn4;
    {
        long row = (long)lm * 64;
        Bc8 = *(const bf16x8*)(wte + row + lk * 8);
        Bc4 = ld_b4(wte + row + 32 + lk * 4);
    }

#pragma unroll 1
    for (int t = 0; t < 9; ++t) {
        if (t < 8) {
            long row = (long)((t + 1) * 16 + lm) * 64;
            Bn8 = *(const bf16x8*)(wte + row + lk * 8);
            Bn4 = ld_b4(wte + row + 32 + lk * 4);
        }
        int dy = t / 3 - 1, dx = t % 3 - 1;
#pragma unroll
        for (int q = 0; q < 2; ++q) {
            int ppx = xA[q] + 1 + dx;
            int bofs = ((rA[q] + 1 + dy) * PWS + ppx) * 96;
            int sw = (ppx & 4) << 2;
            bf16x8 A0 = *(const bf16x8*)(&lds[bofs + ((lk * 16) ^ sw)]);
            bf16x4 A1 = *(const bf16x4*)(&lds[bofs + ((64 + lk * 8) ^ sw)]);
            acc[q] = __builtin_amdgcn_mfma_f32_16x16x32_bf16(A0, Bc8, acc[q], 0, 0, 0);
            acc[q] = mfma_k16(A1, Bc4, acc[q]);
        }
        Bc8 = Bn8; Bc4 = Bn4;
    }

    if (lm < 3) {
#pragma unroll
        for (int q = 0; q < 2; ++q)
#pragma unroll
            for (int rg = 0; rg < 4; ++rg) {
                int pe = (wv * 2 + q) * 16 + lk * 4 + rg;
                int r = pe >> 6, x = pe & 63;
                bounce[(lm * 2 + r) * 64 + x] = acc[q][rg];
            }
    }
    __syncthreads();

    for (int u = threadIdx.x; u < 384; u += 256) {
        int c = u >> 7, r = (u >> 6) & 1, x = u & 63;
        outp[(long)s * 49152 + (long)c * 16384 + (long)(rowb * 2 + r) * 128 + colb * 64 + x] =
            bounce[(c * 2 + r) * 64 + x];
    }
}

// ---------------------------------------------------------------------------
extern "C" void kernel_launch(void* const* d_in, const int* in_sizes, int n_in,
                              void* d_out, int out_size, void* d_ws, size_t ws_size,
                              hipStream_t stream)
{
    const float* inputs  = (const float*)d_in[0];
    const float* cls_w   = (const float*)d_in[1];
    const float* cls_b   = (const float*)d_in[2];
    const float* centers = (const float*)d_in[3];
    const float* head_w  = (const float*)d_in[4];
    const float* head_b  = (const float*)d_in[5];
    const float* bw1     = (const float*)d_in[6];
    const float* bb1     = (const float*)d_in[7];
    const float* bw2     = (const float*)d_in[8];
    const float* bb2     = (const float*)d_in[9];
    const float* body_w  = (const float*)d_in[10];
    const float* body_b  = (const float*)d_in[11];
    const float* up1_w   = (const float*)d_in[12];
    const float* up1_b   = (const float*)d_in[13];
    const float* up2_w   = (const float*)d_in[14];
    const float* up2_b   = (const float*)d_in[15];
    const float* tail_w  = (const float*)d_in[16];
    const float* tail_b  = (const float*)d_in[17];
    float* out = (float*)d_out;

    char* base = (char*)d_ws;
    size_t o = 0;
    auto A = [&](size_t bytes) { size_t r = o; o = (o + bytes + 255) & ~(size_t)255; return r; };

    size_t feat_o  = A(128 * 512 * 4);
    size_t asg_o   = A(512);

    const size_t HEAD_W = (size_t)10 * 9 * 48 * 64;
    const size_t BW_W   = (size_t)80 * 9 * 48 * 64;
    const size_t BODY_W = (size_t)10 * 9 * 48 * 64;
    const size_t UP_W   = (size_t)10 * 9 * 48 * 64;
    const size_t TAIL_W = (size_t)10 * 9 * 16 * 64;

    size_t headw_o = A(HEAD_W * 2);
    size_t bw1_o   = A(BW_W * 2);
    size_t bw2_o   = A(BW_W * 2);
    size_t bodyw_o = A(BODY_W * 2);
    size_t up1w_o  = A(4 * UP_W * 2);
    size_t up2w_o  = A(4 * UP_W * 2);
    size_t tailw_o = A(TAIL_W * 2);

    size_t headb_o = A(10 * 48 * 4);
    size_t bw1b_o  = A(80 * 48 * 4);
    size_t bw2b_o  = A(80 * 48 * 4);
    size_t bodyb_o = A(10 * 48 * 4);
    size_t up1b_o  = A(4 * 10 * 48 * 4);
    size_t up2b_o  = A(4 * 10 * 48 * 4);
    size_t tailb_o = A(10 * 16 * 4);

    size_t fixed_end = o;

    const size_t P32 = (size_t)34 * 34 * 48;
    const size_t PU1 = (size_t)66 * 66 * 48;
    const size_t PU2 = (size_t)130 * 130 * 48;

    // S = trunk chunk samples; SU = up2+tail sub-chunk samples (U2 sized SU)
    int S = 1, SU = 1;
    {
        bool ok = false;
        for (int s_ = NSAMP; s_ >= 1 && !ok; s_ >>= 1)
            for (int su_ = s_; su_ >= 1; su_ >>= 1) {
                size_t need = fixed_end + (size_t)s_ * (4 * P32 + PU1) * 2
                            + (size_t)su_ * PU2 * 2;
                if (need <= ws_size) { S = s_; SU = su_; ok = true; break; }
            }
    }

    short* inclB = (short*)(base + o);
    short* bB = inclB + (size_t)S * P32;
    short* tB = bB + (size_t)S * P32;
    short* hB = tB + (size_t)S * P32;
    short* U1 = hB + (size_t)S * P32;
    short* U2 = U1 + (size_t)S * PU1;

    float* feat   = (float*)(base + feat_o);
    int*   assign = (int*)(base + asg_o);
    short* wbase  = (short*)(base + headw_o);
    float* bbase  = (float*)(base + headb_o);

    short* headwt = (short*)(base + headw_o);
    short* bw1wt  = (short*)(base + bw1_o);
    short* bw2wt  = (short*)(base + bw2_o);
    short* bodywt = (short*)(base + bodyw_o);
    short* up1wt  = (short*)(base + up1w_o);
    short* up2wt  = (short*)(base + up2w_o);
    short* tailwt = (short*)(base + tailw_o);
    float* headbb = (float*)(base + headb_o);
    float* bw1bb  = (float*)(base + bw1b_o);
    float* bw2bb  = (float*)(base + bw2b_o);
    float* bodybb = (float*)(base + bodyb_o);
    float* up1bb  = (float*)(base + up1b_o);
    float* up2bb  = (float*)(base + up2b_o);
    float* tailbb = (float*)(base + tailb_o);

    PrepTable T;
    auto setd = [&](int i, const float* ws_, const float* bs_, int nm, int cop,
                    int cosrc, int coreal, int cireal, int grp,
                    size_t wdo, size_t bdo) {
        T.d[i].wsrc = ws_; T.d[i].bsrc = bs_;
        T.d[i].n_mat = nm; T.d[i].CO_pad = cop; T.d[i].CO_src = cosrc;
        T.d[i].CO_real = coreal; T.d[i].CI_real = cireal; T.d[i].group = grp;
        T.d[i].sz_w = (size_t)nm * 9 * cop * 64;
        T.d[i].sz_b = (size_t)nm * cop;
        T.d[i].wdst = (wdo - headw_o) / 2;
        T.d[i].bdst = (bdo - headb_o) / 4;
    };
    setd(0,  head_w, head_b, 10, 48, 36, 36, 3,  -1, headw_o, headb_o);
    setd(1,  bw1,    bb1,    80, 48, 36, 36, 36, -1, bw1_o,   bw1b_o);
    setd(2,  bw2,    bb2,    80, 48, 36, 36, 36, -1, bw2_o,   bw2b_o);
    setd(3,  body_w, body_b, 10, 48, 36, 36, 36, -1, bodyw_o, bodyb_o);
    for (int g = 0; g < 4; ++g)
        setd(4 + g, up1_w, up1_b, 10, 48, 144, 36, 36, g,
             up1w_o + (size_t)g * UP_W * 2, up1b_o + (size_t)g * 480 * 4);
    for (int g = 0; g < 4; ++g)
        setd(8 + g, up2_w, up2_b, 10, 48, 144, 36, 36, g,
             up2w_o + (size_t)g * UP_W * 2, up2b_o + (size_t)g * 480 * 4);
    setd(12, tail_w, tail_b, 10, 16, 3, 3, 36, -1, tailw_o, tailb_o);

    size_t wtot = 0, btot = 0;
    for (int i = 0; i < 13; ++i) { wtot += T.d[i].sz_w; btot += T.d[i].sz_b; }

    hipLaunchKernelGGL(k_prep, dim3((unsigned)((wtot + btot + 255) / 256)), dim3(256),
                       0, stream, T, wbase, bbase, wtot, btot);

    // combined halo zeroing (U2 buffer holds SU samples)
    {
        HaloTab H;
        short* ps[5] = { inclB, bB, tB, U1, U2 };
        int    hp[5] = { 34, 34, 34, 66, 130 };
        long   ss[5] = { (long)P32, (long)P32, (long)P32, (long)PU1, (long)PU2 };
        int    ns[5] = { S, S, S, S, SU };
        H.cum[0] = 0;
        for (int i = 0; i < 5; ++i) {
            H.p[i] = ps[i]; H.Hp[i] = hp[i]; H.ss[i] = ss[i];
            H.cum[i + 1] = H.cum[i] + (long)ns[i] * (4 * hp[i] - 4) * 6;
        }
        hipLaunchKernelGGL(k_halo_all, dim3((unsigned)((H.cum[5] + 255) / 256)),
                           dim3(256), 0, stream, H);
    }

    hipLaunchKernelGGL(k_cls2, dim3(NSAMP * 64), dim3(128), 0, stream,
                       inputs, cls_w, cls_b, feat);
    hipLaunchKernelGGL(k_assign, dim3(NSAMP), dim3(64), 0, stream,
                       feat, centers, assign);

    const long WES_RES  = 8L * 9 * 48 * 64;
    const long WES_ONE  = 9L * 48 * 64;
    const long WES_TAIL = 9L * 16 * 64;

    for (int bs = 0; bs < NSAMP; bs += S) {
        hipLaunchKernelGGL(k_incl, dim3((S * 1024 + 255) / 256), dim3(256), 0, stream,
                           inputs, inclB, bs, S);
        // head -> bB and hB
        hipLaunchKernelGGL((k_conv_res<2, false>), dim3(S * 8), dim3(256), 0, stream,
                           inclB, (long)P32, headwt, WES_ONE, headbb, 48L,
                           assign, bs, bB, (long)P32, (const short*)nullptr, hB, S);
        // fused residual blocks, ping-pong bB <-> tB
        short* pin = bB;
        short* pout = tB;
        for (int i = 0; i < NBLK; ++i) {
            hipLaunchKernelGGL(k_res_fused, dim3(S * 8), dim3(256), 0, stream,
                               pin, pout,
                               bw1wt + (size_t)i * WES_ONE, bw1bb + i * 48,
                               bw2wt + (size_t)i * WES_ONE, bw2bb + i * 48,
                               WES_RES, 8L * 48, assign, bs, S);
            short* tmp = pin; pin = pout; pout = tmp;
        }
        // body + global skip -> tB (pin == bB after even number of blocks)
        hipLaunchKernelGGL((k_conv_res<1, false>), dim3(S * 8), dim3(256), 0, stream,
                           pin, (long)P32, bodywt, WES_ONE, bodybb, 48L,
                           assign, bs, tB, (long)P32, hB, (short*)nullptr, S);
        // up1 merged -> U1
        hipLaunchKernelGGL((k_conv_up<32, 2>), dim3(S * 16), dim3(256), 0, stream,
                           tB, (long)P32, up1wt, (long)UP_W, WES_ONE,
                           up1bb, 480L, 48L, assign, bs, U1, (long)PU1, S);
        // up2 + tail in SU-sized sub-chunks (U2 holds SU samples)
        for (int hb = 0; hb < S; hb += SU) {
            hipLaunchKernelGGL((k_conv_up<64, 1>), dim3(SU * 64), dim3(256), 0, stream,
                               U1 + (size_t)hb * PU1, (long)PU1, up2wt, (long)UP_W, WES_ONE,
                               up2bb, 480L, 48L, assign, bs + hb, U2, (long)PU2, SU);
            hipLaunchKernelGGL(k_conv_tail, dim3(SU * 128), dim3(256), 0, stream,
                               U2, (long)PU2, tailwt, WES_TAIL, tailbb, 16L,
                               assign, bs + hb, out + (size_t)(bs + hb) * 49152, SU);
        }
    }
}

// Round 11
// 910.217 us; speedup vs baseline: 1.3213x; 1.2937x over previous
//
#include <hip/hip_runtime.h>
#include <hip/hip_bf16.h>

// ---------------------------------------------------------------------------
// LiveSR round 11: 8-output-rows-per-block trunk kernels.
//  - k_res_fused: 8 rows/block (conv1 redundancy 1.5->1.25x, stage amp 2->1.5x),
//    LDS 71.8KB = 2 blocks/CU, grid S*4=512 exactly resident.
//  - k_conv_res: 8 rows/block, bounce aliased over act tile (53.2KB, 3/CU).
//  - everything else = round 10 (S=128 + SU subchunk, unroll-1 tap loops,
//    verified-MFMA-only K=48 split, 96B/px records).
// ---------------------------------------------------------------------------

#define NSAMP 128
#define NSUB  10
#define NBLK  8
#define P32E  (34 * 34 * 48)

typedef __attribute__((ext_vector_type(8))) short bf16x8;
typedef __attribute__((ext_vector_type(4))) short bf16x4;
typedef __attribute__((ext_vector_type(4))) float f32x4;

// zero-extended partial-K MFMA (ch32-47): both operands place ch32+4lk+j at
// k=8lk+j; padded k-slots contribute 0. Only the HW-verified shape is used.
__device__ inline f32x4 mfma_k16(bf16x4 a, bf16x8 b8, f32x4 c) {
    bf16x8 a8 = { a[0], a[1], a[2], a[3], (short)0, (short)0, (short)0, (short)0 };
    return __builtin_amdgcn_mfma_f32_16x16x32_bf16(a8, b8, c, 0, 0, 0);
}
__device__ inline bf16x8 ld_b4(const short* p) {
    bf16x4 t = *(const bf16x4*)p;
    bf16x8 r = { t[0], t[1], t[2], t[3], (short)0, (short)0, (short)0, (short)0 };
    return r;
}

__device__ inline short f2bf(float f) {
    union { float f; unsigned u; } v; v.f = f;
    unsigned r = (v.u + 0x7FFFu + ((v.u >> 16) & 1u)) >> 16;
    return (short)r;
}
__device__ inline float bf2f(short s) {
    union { unsigned u; float f; } v; v.u = ((unsigned)(unsigned short)s) << 16;
    return v.f;
}

union U16 { uint4 u; short s[8]; };

// sample->XCD-stable bijective swizzle
template<int RB>
__device__ inline void swz(int p, int S, int& s, int& rb) {
    if ((S & 7) == 0) {
        int x = p & 7, q = p >> 3;
        int sp = q / RB;
        s = x * (S >> 3) + sp;
        rb = q - sp * RB;
    } else {
        s = p / RB; rb = p - s * RB;
    }
}

// ---------------- weight / bias preprocessing -------------------------------
struct PrepDesc {
    const float* wsrc; const float* bsrc;
    int n_mat, CO_pad, CO_src, CO_real, CI_real, group;
    size_t sz_w, sz_b, wdst, bdst;
};
struct PrepTable { PrepDesc d[13]; };

__global__ __launch_bounds__(256)
void k_prep(PrepTable T, short* __restrict__ wb, float* __restrict__ bb,
            size_t wtot, size_t btot)
{
    size_t id = (size_t)blockIdx.x * 256 + threadIdx.x;
    if (id < wtot) {
        int s = 0; size_t off = id;
        while (off >= T.d[s].sz_w) { off -= T.d[s].sz_w; ++s; }
        const PrepDesc& D = T.d[s];
        int ci = (int)(off & 63);
        size_t q = off >> 6;
        int co = (int)(q % D.CO_pad);
        size_t q2 = q / D.CO_pad;
        int t = (int)(q2 % 9);
        int m = (int)(q2 / 9);
        float v = 0.f;
        if (co < D.CO_real && ci < D.CI_real) {
            int cs = (D.group >= 0) ? co * 4 + D.group : co;
            v = D.wsrc[(((size_t)m * D.CO_src + cs) * D.CI_real + ci) * 9 + t];
        }
        wb[D.wdst + off] = f2bf(v);
    } else if (id < wtot + btot) {
        size_t off = id - wtot;
        int s = 0;
        while (off >= T.d[s].sz_b) { off -= T.d[s].sz_b; ++s; }
        const PrepDesc& D = T.d[s];
        int co = (int)(off % D.CO_pad);
        int m  = (int)(off / D.CO_pad);
        float v = 0.f;
        if (co < D.CO_real) {
            int cs = (D.group >= 0) ? co * 4 + D.group : co;
            v = D.bsrc[(size_t)m * D.CO_src + cs];
        }
        bb[D.bdst + off] = v;
    }
}

// combined halo zeroing (per-buffer sample counts encoded in cum[])
struct HaloTab { short* p[5]; int Hp[5]; long ss[5]; long cum[6]; };

__global__ __launch_bounds__(256)
void k_halo_all(HaloTab H)
{
    long u = (long)blockIdx.x * 256 + threadIdx.x;
    int b = 0;
    while (b < 5 && u >= H.cum[b + 1]) ++b;
    if (b >= 5) return;
    u -= H.cum[b];
    int Hp = H.Hp[b];
    int perim = 4 * Hp - 4;
    int k = (int)(u % 6);
    long q = u / 6;
    int e = (int)(q % perim);
    int s = (int)(q / perim);
    int r, c;
    if (e < Hp)            { r = 0;       c = e; }
    else if (e < 2 * Hp)   { r = Hp - 1;  c = e - Hp; }
    else { int e2 = e - 2 * Hp; r = 1 + (e2 >> 1); c = (e2 & 1) ? Hp - 1 : 0; }
    *(uint4*)(H.p[b] + (long)s * H.ss[b] + ((long)r * Hp + c) * 48 + k * 8) =
        make_uint4(0u, 0u, 0u, 0u);
}

// input fp32 NCHW -> padded channels-last bf16 [34][34][48]
__global__ __launch_bounds__(256)
void k_incl(const float* __restrict__ in, short* __restrict__ dst, int base, int S)
{
    int idx = blockIdx.x * 256 + threadIdx.x;
    if (idx >= S * 1024) return;
    int s = idx >> 10, p = idx & 1023;
    int y = p >> 5, x = p & 31;
    const float* src = in + (size_t)(base + s) * 3072 + p;
    short* d = dst + (((long)s * 34 + (y + 1)) * 34 + (x + 1)) * 48;
    uint4 z = make_uint4(0u, 0u, 0u, 0u);
    U16 a; a.u = z;
    a.s[0] = f2bf(src[0]);
    a.s[1] = f2bf(src[1024]);
    a.s[2] = f2bf(src[2048]);
    ((uint4*)d)[0] = a.u;
#pragma unroll
    for (int k = 1; k < 6; ++k) ((uint4*)d)[k] = z;
}

// ---------------- classifier (fp32, exact) ----------------------------------
__global__ __launch_bounds__(128)
void k_cls2(const float* __restrict__ in, const float* __restrict__ w,
            const float* __restrict__ bias, float* __restrict__ feat)
{
    int bid = blockIdx.x;
    int n = bid >> 6, cg = bid & 63;
    __shared__ float wl[8 * 27];
    const float* wp = w + (size_t)(cg * 8) * 27;
    for (int i = threadIdx.x; i < 216; i += 128) wl[i] = wp[i];
    __syncthreads();

    int tx = threadIdx.x & 3;
    int y  = threadIdx.x >> 2;
    int x0 = tx * 8;
    const float* x = in + (size_t)n * 3072;

    float acc[8][8];
#pragma unroll
    for (int j = 0; j < 8; ++j) {
        float bv = bias[cg * 8 + j];
#pragma unroll
        for (int k = 0; k < 8; ++k) acc[j][k] = bv;
    }

#pragma unroll
    for (int ci = 0; ci < 3; ++ci) {
        const float* pl = x + ci * 1024;
        float r0[10], r1[10], r2[10];
        {
            const float4* v = (const float4*)(pl + y * 32 + x0);
            float4 a = v[0], b = v[1];
            r1[1]=a.x; r1[2]=a.y; r1[3]=a.z; r1[4]=a.w;
            r1[5]=b.x; r1[6]=b.y; r1[7]=b.z; r1[8]=b.w;
            r1[0] = (x0 > 0)  ? pl[y*32 + x0 - 1] : 0.f;
            r1[9] = (x0 < 24) ? pl[y*32 + x0 + 8] : 0.f;
        }
        if (y > 0) {
            const float* row = pl + (y-1) * 32;
            const float4* v = (const float4*)(row + x0);
            float4 a = v[0], b = v[1];
            r0[1]=a.x; r0[2]=a.y; r0[3]=a.z; r0[4]=a.w;
            r0[5]=b.x; r0[6]=b.y; r0[7]=b.z; r0[8]=b.w;
            r0[0] = (x0 > 0)  ? row[x0 - 1] : 0.f;
            r0[9] = (x0 < 24) ? row[x0 + 8] : 0.f;
        } else {
#pragma unroll
            for (int k = 0; k < 10; ++k) r0[k] = 0.f;
        }
        if (y < 31) {
            const float* row = pl + (y+1) * 32;
            const float4* v = (const float4*)(row + x0);
            float4 a = v[0], b = v[1];
            r2[1]=a.x; r2[2]=a.y; r2[3]=a.z; r2[4]=a.w;
            r2[5]=b.x; r2[6]=b.y; r2[7]=b.z; r2[8]=b.w;
            r2[0] = (x0 > 0)  ? row[x0 - 1] : 0.f;
            r2[9] = (x0 < 24) ? row[x0 + 8] : 0.f;
        } else {
#pragma unroll
            for (int k = 0; k < 10; ++k) r2[k] = 0.f;
        }
#pragma unroll
        for (int j = 0; j < 8; ++j) {
            const float* ww = &wl[(j * 3 + ci) * 9];
            float w0=ww[0],w1=ww[1],w2=ww[2],w3=ww[3],w4=ww[4],
                  w5=ww[5],w6=ww[6],w7=ww[7],w8=ww[8];
#pragma unroll
            for (int k = 0; k < 8; ++k)
                acc[j][k] += r0[k]*w0 + r0[k+1]*w1 + r0[k+2]*w2
                           + r1[k]*w3 + r1[k+1]*w4 + r1[k+2]*w5
                           + r2[k]*w6 + r2[k+1]*w7 + r2[k+2]*w8;
        }
    }

    float ps[8];
#pragma unroll
    for (int j = 0; j < 8; ++j) {
        float s = 0.f;
#pragma unroll
        for (int k = 0; k < 8; ++k) s += fmaxf(acc[j][k], 0.f);
        ps[j] = s;
    }
#pragma unroll
    for (int j = 0; j < 8; ++j) {
#pragma unroll
        for (int off = 32; off; off >>= 1) ps[j] += __shfl_down(ps[j], off);
    }
    __shared__ float red[2][8];
    int wv = threadIdx.x >> 6, ln = threadIdx.x & 63;
    if (ln == 0) {
#pragma unroll
        for (int j = 0; j < 8; ++j) red[wv][j] = ps[j];
    }
    __syncthreads();
    if (threadIdx.x < 8)
        feat[(size_t)n * 512 + cg * 8 + threadIdx.x] =
            (red[0][threadIdx.x] + red[1][threadIdx.x]) * (1.0f / 1024.0f);
}

__global__ __launch_bounds__(64)
void k_assign(const float* __restrict__ feat, const float* __restrict__ centers,
              int* __restrict__ assign)
{
    int n = blockIdx.x;
    int t = threadIdx.x;
    const float* f = feat + (size_t)n * 512;
    float best = -1e30f;
    int bi = 0;
    for (int k = 0; k < NSUB; ++k) {
        float s = 0.f;
        for (int d = t; d < 512; d += 64) {
            float df = f[d] - centers[(size_t)k * 512 + d];
            s += df * df;
        }
#pragma unroll
        for (int off = 32; off; off >>= 1) s += __shfl_down(s, off);
        if (t == 0) {
            float sc = 1.0f / s;
            if (sc > best) { best = sc; bi = k; }
        }
    }
    if (t == 0) assign[n] = bi;
}

// ---------------- residual-type single conv (head / body), 8 rows/block -----
// EPI: 0 = store, 1 = store + skip-add, 2 = store to out and out2
template<int EPI, bool RELU>
__global__ __launch_bounds__(256)
void k_conv_res(const short* __restrict__ act, long act_ss,
                const short* __restrict__ wt, long wt_es,
                const float* __restrict__ bias, long b_es,
                const int* __restrict__ assign, int abase,
                short* __restrict__ out, long out_ss,
                const short* __restrict__ skip,
                short* __restrict__ out2, int S)
{
    constexpr int PW = 34, LROWS = 10, RB = 4;
    // act tile 10*34*96 = 32640; bounce 256*52*4 = 53248 (aliased over act)
    __shared__ __align__(16) char lds[53248];
    float* bounce = (float*)lds;

    int s, rb;
    swz<RB>(blockIdx.x, S, s, rb);
    int a = assign[abase + s];
    const short* wte = wt + (long)a * wt_es;
    const float* be  = bias + (long)a * b_es;

    {
        const short* src = act + (long)s * act_ss + (long)rb * 8 * PW * 48;
        constexpr int NCH = LROWS * PW * 6;
        for (int i = threadIdx.x; i < NCH; i += 256) {
            int pl = i / 6, c = i - pl * 6;
            int px = pl % PW;
            uint4 v = *(const uint4*)(src + (long)pl * 48 + c * 8);
            *(uint4*)(&lds[pl * 96 + ((c * 16) ^ ((px & 4) << 2))]) = v;
        }
    }
    __syncthreads();

    int lane = threadIdx.x & 63, wv = threadIdx.x >> 6;
    int lm = lane & 15, lk = lane >> 4;

    f32x4 acc[4][3];
#pragma unroll
    for (int nf = 0; nf < 3; ++nf) {
        float bb = be[nf * 16 + lm];
        f32x4 iv = { bb, bb, bb, bb };
#pragma unroll
        for (int q = 0; q < 4; ++q) acc[q][nf] = iv;
    }
    int rA[4], xA[4];
#pragma unroll
    for (int q = 0; q < 4; ++q) {
        int pl = (wv * 4 + q) * 16 + lm;
        rA[q] = pl >> 5; xA[q] = pl & 31;
    }

    bf16x8 Bc8[3], Bn8[3], Bc4[3], Bn4[3];
#pragma unroll
    for (int nf = 0; nf < 3; ++nf) {
        long row = (long)(nf * 16 + lm) * 64;
        Bc8[nf] = *(const bf16x8*)(wte + row + lk * 8);
        Bc4[nf] = ld_b4(wte + row + 32 + lk * 4);
    }

#pragma unroll 1
    for (int t = 0; t < 9; ++t) {
        if (t < 8) {
#pragma unroll
            for (int nf = 0; nf < 3; ++nf) {
                long row = (long)((t + 1) * 48 + nf * 16 + lm) * 64;
                Bn8[nf] = *(const bf16x8*)(wte + row + lk * 8);
                Bn4[nf] = ld_b4(wte + row + 32 + lk * 4);
            }
        }
        int dy = t / 3 - 1, dx = t % 3 - 1;
#pragma unroll
        for (int q = 0; q < 4; ++q) {
            int ppx = xA[q] + 1 + dx;
            int bofs = ((rA[q] + 1 + dy) * PW + ppx) * 96;
            int sw = (ppx & 4) << 2;
            bf16x8 A0 = *(const bf16x8*)(&lds[bofs + ((lk * 16) ^ sw)]);
            bf16x4 A1 = *(const bf16x4*)(&lds[bofs + ((64 + lk * 8) ^ sw)]);
#pragma unroll
            for (int nf = 0; nf < 3; ++nf) {
                acc[q][nf] = __builtin_amdgcn_mfma_f32_16x16x32_bf16(A0, Bc8[nf], acc[q][nf], 0, 0, 0);
                acc[q][nf] = mfma_k16(A1, Bc4[nf], acc[q][nf]);
            }
        }
#pragma unroll
        for (int nf = 0; nf < 3; ++nf) {
            Bc8[nf] = Bn8[nf]; Bc4[nf] = Bn4[nf];
        }
    }
    __syncthreads();   // all act reads done -> alias bounce

#pragma unroll
    for (int q = 0; q < 4; ++q)
#pragma unroll
        for (int nf = 0; nf < 3; ++nf)
#pragma unroll
            for (int rg = 0; rg < 4; ++rg) {
                int pe = (wv * 4 + q) * 16 + lk * 4 + rg;
                float v = acc[q][nf][rg];
                if (RELU) v = fmaxf(v, 0.f);
                bounce[pe * 52 + nf * 16 + lm] = v;
            }
    __syncthreads();

    for (int u = threadIdx.x; u < 1536; u += 256) {
        int px = u / 6, k = u - px * 6;
        int r = px >> 5, x = px & 31;
        long off = (long)s * out_ss + ((long)(rb * 8 + r + 1) * PW + (x + 1)) * 48 + k * 8;
        f32x4 v0 = *(f32x4*)&bounce[px * 52 + k * 8];
        f32x4 v1 = *(f32x4*)&bounce[px * 52 + k * 8 + 4];
        if (EPI == 1) {
            U16 sk; sk.u = *(const uint4*)(skip + off);
            v0.x += bf2f(sk.s[0]); v0.y += bf2f(sk.s[1]);
            v0.z += bf2f(sk.s[2]); v0.w += bf2f(sk.s[3]);
            v1.x += bf2f(sk.s[4]); v1.y += bf2f(sk.s[5]);
            v1.z += bf2f(sk.s[6]); v1.w += bf2f(sk.s[7]);
        }
        U16 o;
        o.s[0] = f2bf(v0.x); o.s[1] = f2bf(v0.y); o.s[2] = f2bf(v0.z); o.s[3] = f2bf(v0.w);
        o.s[4] = f2bf(v1.x); o.s[5] = f2bf(v1.y); o.s[6] = f2bf(v1.z); o.s[7] = f2bf(v1.w);
        *(uint4*)(out + off) = o.u;
        if (EPI == 2) *(uint4*)(out2 + off) = o.u;
    }
}

// ---------------- fused residual block, 8 output rows/block -----------------
// out = in + conv2(relu(conv1(in))); t kept in LDS.
__global__ __launch_bounds__(256)
void k_res_fused(const short* __restrict__ in, short* __restrict__ outb,
                 const short* __restrict__ wt1, const float* __restrict__ b1,
                 const short* __restrict__ wt2, const float* __restrict__ b2,
                 long wt_es, long b_es,
                 const int* __restrict__ assign, int abase, int S)
{
    constexpr int PW = 34;
    // b: 12 padded rows (R0-1..R0+10) = 12*34*96 = 39168
    // t: 10 rows (image R0-1..R0+8)  = 10*34*96 = 32640
    // bounce (256px * 50 f32 = 51200) aliased at base after both phases done
    __shared__ __align__(16) char lds[39168 + 32640];
    char* bst = lds;
    char* tst = lds + 39168;
    float* bounce = (float*)lds;

    int s, rb;
    swz<4>(blockIdx.x, S, s, rb);
    int a = assign[abase + s];
    const short* w1 = wt1 + (long)a * wt_es;
    const short* w2 = wt2 + (long)a * wt_es;
    const float* bb1 = b1 + (long)a * b_es;
    const float* bb2 = b2 + (long)a * b_es;
    int R0 = rb * 8;
    uint4 z = make_uint4(0u, 0u, 0u, 0u);

    // zero t region (col halos + out-of-range rows must stay zero)
    for (int i = threadIdx.x; i < 10 * PW * 6; i += 256)
        *(uint4*)(&tst[i * 16]) = z;
    // stage b: padded rows R0-1 .. R0+10
    {
        const short* src = in + (long)s * P32E;
        for (int i = threadIdx.x; i < 12 * PW * 6; i += 256) {
            int pl = i / 6, c = i - pl * 6;
            int lr = pl / PW, pc = pl - lr * PW;
            int pr = R0 - 1 + lr;
            uint4 v = z;
            if (pr >= 0 && pr <= 33)
                v = *(const uint4*)(src + ((long)pr * PW + pc) * 48 + c * 8);
            *(uint4*)(&bst[pl * 96 + ((c * 16) ^ ((pc & 4) << 2))]) = v;
        }
    }
    __syncthreads();

    int lane = threadIdx.x & 63, wv = threadIdx.x >> 6;
    int lm = lane & 15, lk = lane >> 4;

    // ================= conv1: t image rows R0-1 .. R0+8 (relu) ===========
    {
        int tiv[5], xhv[5];
#pragma unroll
        for (int j = 0; j < 5; ++j) {
            int m = wv * 5 + j;
            tiv[j] = m >> 1; xhv[j] = m & 1;
        }
        f32x4 acc[5][3];
#pragma unroll
        for (int nf = 0; nf < 3; ++nf) {
            float bv = bb1[nf * 16 + lm];
            f32x4 iv = { bv, bv, bv, bv };
#pragma unroll
            for (int j = 0; j < 5; ++j) acc[j][nf] = iv;
        }

        bf16x8 Bc8[3], Bn8[3], Bc4[3], Bn4[3];
#pragma unroll
        for (int nf = 0; nf < 3; ++nf) {
            long row = (long)(nf * 16 + lm) * 64;
            Bc8[nf] = *(const bf16x8*)(w1 + row + lk * 8);
            Bc4[nf] = ld_b4(w1 + row + 32 + lk * 4);
        }

#pragma unroll 1
        for (int t = 0; t < 9; ++t) {
            if (t < 8) {
#pragma unroll
                for (int nf = 0; nf < 3; ++nf) {
                    long row = (long)((t + 1) * 48 + nf * 16 + lm) * 64;
                    Bn8[nf] = *(const bf16x8*)(w1 + row + lk * 8);
                    Bn4[nf] = ld_b4(w1 + row + 32 + lk * 4);
                }
            }
            int dy = t / 3, dx = t % 3 - 1;
#pragma unroll
            for (int j = 0; j < 5; ++j) {
                int pcol = xhv[j] * 16 + lm + 1 + dx;
                int bofs = ((tiv[j] + dy) * PW + pcol) * 96;
                int sw = (pcol & 4) << 2;
                bf16x8 A0 = *(const bf16x8*)(&bst[bofs + ((lk * 16) ^ sw)]);
                bf16x4 A1 = *(const bf16x4*)(&bst[bofs + ((64 + lk * 8) ^ sw)]);
#pragma unroll
                for (int nf = 0; nf < 3; ++nf) {
                    acc[j][nf] = __builtin_amdgcn_mfma_f32_16x16x32_bf16(A0, Bc8[nf], acc[j][nf], 0, 0, 0);
                    acc[j][nf] = mfma_k16(A1, Bc4[nf], acc[j][nf]);
                }
            }
#pragma unroll
            for (int nf = 0; nf < 3; ++nf) {
                Bc8[nf] = Bn8[nf]; Bc4[nf] = Bn4[nf];
            }
        }

        // write t (relu) into t stage; image rows outside [0,31] stay zero
#pragma unroll
        for (int j = 0; j < 5; ++j) {
            int tr = R0 - 1 + tiv[j];
            if (tr < 0 || tr > 31) continue;
#pragma unroll
            for (int nf = 0; nf < 3; ++nf) {
                int chb = 2 * (nf * 16 + lm);
#pragma unroll
                for (int rg = 0; rg < 4; ++rg) {
                    int pc = xhv[j] * 16 + lk * 4 + rg + 1;
                    float v = fmaxf(acc[j][nf][rg], 0.f);
                    *(short*)(&tst[(tiv[j] * PW + pc) * 96 + (chb ^ ((pc & 4) << 2))]) = f2bf(v);
                }
            }
        }
    }
    __syncthreads();

    // ================= conv2 + skip: out rows R0 .. R0+7 =================
    f32x4 accout[4][3];
    {
        int oiv[4], xhv2[4];
#pragma unroll
        for (int j = 0; j < 4; ++j) {
            int m2 = wv * 4 + j;
            oiv[j] = m2 >> 1; xhv2[j] = m2 & 1;
        }
        f32x4 acc[4][3];
#pragma unroll
        for (int nf = 0; nf < 3; ++nf) {
            float bv = bb2[nf * 16 + lm];
            f32x4 iv = { bv, bv, bv, bv };
#pragma unroll
            for (int j = 0; j < 4; ++j) acc[j][nf] = iv;
        }

        bf16x8 Bc8[3], Bn8[3], Bc4[3], Bn4[3];
#pragma unroll
        for (int nf = 0; nf < 3; ++nf) {
            long row = (long)(nf * 16 + lm) * 64;
            Bc8[nf] = *(const bf16x8*)(w2 + row + lk * 8);
            Bc4[nf] = ld_b4(w2 + row + 32 + lk * 4);
        }

#pragma unroll 1
        for (int t = 0; t < 9; ++t) {
            if (t < 8) {
#pragma unroll
                for (int nf = 0; nf < 3; ++nf) {
                    long row = (long)((t + 1) * 48 + nf * 16 + lm) * 64;
                    Bn8[nf] = *(const bf16x8*)(w2 + row + lk * 8);
                    Bn4[nf] = ld_b4(w2 + row + 32 + lk * 4);
                }
            }
            int dy = t / 3, dx = t % 3 - 1;
#pragma unroll
            for (int j = 0; j < 4; ++j) {
                int pcol = xhv2[j] * 16 + lm + 1 + dx;
                int bofs = ((oiv[j] + dy) * PW + pcol) * 96;
                int sw = (pcol & 4) << 2;
                bf16x8 A0 = *(const bf16x8*)(&tst[bofs + ((lk * 16) ^ sw)]);
                bf16x4 A1 = *(const bf16x4*)(&tst[bofs + ((64 + lk * 8) ^ sw)]);
#pragma unroll
                for (int nf = 0; nf < 3; ++nf) {
                    acc[j][nf] = __builtin_amdgcn_mfma_f32_16x16x32_bf16(A0, Bc8[nf], acc[j][nf], 0, 0, 0);
                    acc[j][nf] = mfma_k16(A1, Bc4[nf], acc[j][nf]);
                }
            }
#pragma unroll
            for (int nf = 0; nf < 3; ++nf) {
                Bc8[nf] = Bn8[nf]; Bc4[nf] = Bn4[nf];
            }
        }

        // skip-add from staged b (out row R0+oi = b local row oi+2)
#pragma unroll
        for (int j = 0; j < 4; ++j)
#pragma unroll
            for (int nf = 0; nf < 3; ++nf) {
                int chb = 2 * (nf * 16 + lm);
                f32x4 r = acc[j][nf];
#pragma unroll
                for (int rg = 0; rg < 4; ++rg) {
                    int pc = xhv2[j] * 16 + lk * 4 + rg + 1;
                    short sv = *(const short*)(&bst[((oiv[j] + 2) * PW + pc) * 96 + (chb ^ ((pc & 4) << 2))]);
                    r[rg] += bf2f(sv);
                }
                accout[j][nf] = r;
            }
    }
    __syncthreads();   // all bst/tst reads done -> safe to alias bounce

#pragma unroll
    for (int j = 0; j < 4; ++j) {
        int m2 = wv * 4 + j;
        int pebase = (m2 >> 1) * 32 + (m2 & 1) * 16;
#pragma unroll
        for (int nf = 0; nf < 3; ++nf)
#pragma unroll
            for (int rg = 0; rg < 4; ++rg) {
                int pe = pebase + lk * 4 + rg;   // 0..255
                bounce[pe * 50 + nf * 16 + lm] = accout[j][nf][rg];
            }
    }
    __syncthreads();

    for (int u = threadIdx.x; u < 1536; u += 256) {
        int px = u / 6, kk = u - px * 6;
        int oi = px >> 5, col = px & 31;
        long off = (long)s * P32E + ((long)(R0 + oi + 1) * PW + (col + 1)) * 48 + kk * 8;
        U16 o;
#pragma unroll
        for (int jj = 0; jj < 8; ++jj) o.s[jj] = f2bf(bounce[px * 50 + kk * 8 + jj]);
        *(uint4*)(outb + off) = o.u;
    }
}

// ---------------- merged 4-group up-conv (pixel shuffle fused) --------------
template<int W, int INROWS>
__global__ __launch_bounds__(256)
void k_conv_up(const short* __restrict__ act, long act_ss,
               const short* __restrict__ wt, long grp_stride, long wt_es,
               const float* __restrict__ bias, long bgrp_stride, long b_es,
               const int* __restrict__ assign, int abase,
               short* __restrict__ out, long out_ss, int S)
{
    constexpr int PW = W + 2, LROWS = INROWS + 2, RB = W / INROWS;
    constexpr int OUTR = 2 * INROWS, OUTC = 2 * W, OPW = 2 * W + 2;
    constexpr int QF = INROWS * W / 16;
    constexpr int ACT_SZ = LROWS * PW * 96;
    constexpr int BNC_SZ = 6 * OUTR * OUTC * 16;
    static_assert(OUTR * OUTC == 256, "plane size must be 256 slots");
    __shared__ __align__(16) char lds[(ACT_SZ > BNC_SZ) ? ACT_SZ : BNC_SZ];
    short* bounce = (short*)lds;   // aliased over act after MFMA

    int s, rb;
    swz<RB>(blockIdx.x, S, s, rb);
    int a = assign[abase + s];
    int wv = threadIdx.x >> 6;
    const short* wte = wt + (long)wv * grp_stride + (long)a * wt_es;
    const float* be  = bias + (long)wv * bgrp_stride + (long)a * b_es;

    {
        const short* src = act + (long)s * act_ss + (long)rb * INROWS * PW * 48;
        constexpr int NCH = LROWS * PW * 6;
        for (int i = threadIdx.x; i < NCH; i += 256) {
            int pl = i / 6, c = i - pl * 6;
            int px = pl % PW;
            uint4 v = *(const uint4*)(src + (long)pl * 48 + c * 8);
            *(uint4*)(&lds[pl * 96 + ((c * 16) ^ ((px & 4) << 2))]) = v;
        }
    }
    __syncthreads();

    int lane = threadIdx.x & 63;
    int lm = lane & 15, lk = lane >> 4;
    int dy = wv >> 1, dx2 = wv & 1;

    f32x4 acc[QF][3];
#pragma unroll
    for (int nf = 0; nf < 3; ++nf) {
        float bb = be[nf * 16 + lm];
        f32x4 iv = { bb, bb, bb, bb };
#pragma unroll
        for (int qf = 0; qf < QF; ++qf) acc[qf][nf] = iv;
    }
    int rA[QF], xA[QF];
#pragma unroll
    for (int qf = 0; qf < QF; ++qf) {
        int pl = qf * 16 + lm;
        rA[qf] = pl / W; xA[qf] = pl % W;
    }

    bf16x8 Bc8[3], Bn8[3], Bc4[3], Bn4[3];
#pragma unroll
    for (int nf = 0; nf < 3; ++nf) {
        long row = (long)(nf * 16 + lm) * 64;
        Bc8[nf] = *(const bf16x8*)(wte + row + lk * 8);
        Bc4[nf] = ld_b4(wte + row + 32 + lk * 4);
    }

#pragma unroll 1
    for (int t = 0; t < 9; ++t) {
        if (t < 8) {
#pragma unroll
            for (int nf = 0; nf < 3; ++nf) {
                long row = (long)((t + 1) * 48 + nf * 16 + lm) * 64;
                Bn8[nf] = *(const bf16x8*)(wte + row + lk * 8);
                Bn4[nf] = ld_b4(wte + row + 32 + lk * 4);
            }
        }
        int tdy = t / 3 - 1, tdx = t % 3 - 1;
#pragma unroll
        for (int qf = 0; qf < QF; ++qf) {
            int ppx = xA[qf] + 1 + tdx;
            int bofs = ((rA[qf] + 1 + tdy) * PW + ppx) * 96;
            int sw = (ppx & 4) << 2;
            bf16x8 A0 = *(const bf16x8*)(&lds[bofs + ((lk * 16) ^ sw)]);
            bf16x4 A1 = *(const bf16x4*)(&lds[bofs + ((64 + lk * 8) ^ sw)]);
#pragma unroll
            for (int nf = 0; nf < 3; ++nf) {
                acc[qf][nf] = __builtin_amdgcn_mfma_f32_16x16x32_bf16(A0, Bc8[nf], acc[qf][nf], 0, 0, 0);
                acc[qf][nf] = mfma_k16(A1, Bc4[nf], acc[qf][nf]);
            }
        }
#pragma unroll
        for (int nf = 0; nf < 3; ++nf) {
            Bc8[nf] = Bn8[nf]; Bc4[nf] = Bn4[nf];
        }
    }
    __syncthreads();   // act reads done -> alias bounce

    // XOR-permuted bounce slots (involution, conflict-free writes)
#pragma unroll
    for (int qf = 0; qf < QF; ++qf)
#pragma unroll
        for (int nf = 0; nf < 3; ++nf)
#pragma unroll
            for (int rg = 0; rg < 4; ++rg) {
                int pe = qf * 16 + lk * 4 + rg;
                int r = pe / W, x = pe % W;
                int plane = nf * 2 + (lm >> 3);
                int slot = plane * 256 + (2 * r + dy) * OUTC + 2 * x + dx2;
                int phys = slot ^ ((slot >> 3) & 7) ^ (((slot >> 8) & 1) << 2);
                bounce[phys * 8 + (lm & 7)] = f2bf(acc[qf][nf][rg]);
            }
    __syncthreads();

    for (int u = threadIdx.x; u < 6 * 256; u += 256) {
        int k = u >> 8;
        int rem = u & 255;
        int rl = rem / OUTC, col = rem - rl * OUTC;
        int phys = u ^ ((u >> 3) & 7) ^ (((u >> 8) & 1) << 2);
        long off = (long)s * out_ss + ((long)(rb * OUTR + rl + 1) * OPW + (col + 1)) * 48 + k * 8;
        *(uint4*)(out + off) = ((uint4*)bounce)[phys];
    }
}

// ---------------- tail conv (36->3 @128x128) -> fp32 NCHW -------------------
__global__ __launch_bounds__(256)
void k_conv_tail(const short* __restrict__ act, long act_ss,
                 const short* __restrict__ wt, long wt_es,
                 const float* __restrict__ bias, long b_es,
                 const int* __restrict__ assign, int abase,
                 float* __restrict__ outp, int S)
{
    constexpr int PWS = 66, LROWS = 4, RB = 128;
    __shared__ __align__(16) char lds[LROWS * PWS * 96 + 3 * 2 * 64 * 4];
    float* bounce = (float*)&lds[LROWS * PWS * 96];

    int s, rb;
    swz<RB>(blockIdx.x, S, s, rb);
    int rowb = rb >> 1, colb = rb & 1;
    int a = assign[abase + s];
    const short* wte = wt + (long)a * wt_es;
    const float* be  = bias + (long)a * b_es;

    {
        constexpr int NCH = LROWS * PWS * 6;
        for (int i = threadIdx.x; i < NCH; i += 256) {
            int pl = i / 6, c = i - pl * 6;
            int lr = pl / PWS, lc = pl - lr * PWS;
            uint4 v = *(const uint4*)(act + (long)s * act_ss +
                        ((long)(rowb * 2 + lr) * 130 + colb * 64 + lc) * 48 + c * 8);
            *(uint4*)(&lds[pl * 96 + ((c * 16) ^ ((lc & 4) << 2))]) = v;
        }
    }
    __syncthreads();

    int lane = threadIdx.x & 63, wv = threadIdx.x >> 6;
    int lm = lane & 15, lk = lane >> 4;

    f32x4 acc[2];
    {
        float bb = be[lm];
        f32x4 iv = { bb, bb, bb, bb };
        acc[0] = iv; acc[1] = iv;
    }
    int rA[2], xA[2];
#pragma unroll
    for (int q = 0; q < 2; ++q) {
        int pl = (wv * 2 + q) * 16 + lm;
        rA[q] = pl >> 6; xA[q] = pl & 63;
    }

    bf16x8 Bc8, Bn8, Bc4, Bn4;
    {
        long row = (long)lm * 64;
        Bc8 = *(const bf16x8*)(wte + row + lk * 8);
        Bc4 = ld_b4(wte + row + 32 + lk * 4);
    }

#pragma unroll 1
    for (int t = 0; t < 9; ++t) {
        if (t < 8) {
            long row = (long)((t + 1) * 16 + lm) * 64;
            Bn8 = *(const bf16x8*)(wte + row + lk * 8);
            Bn4 = ld_b4(wte + row + 32 + lk * 4);
        }
        int dy = t / 3 - 1, dx = t % 3 - 1;
#pragma unroll
        for (int q = 0; q < 2; ++q) {
            int ppx = xA[q] + 1 + dx;
            int bofs = ((rA[q] + 1 + dy) * PWS + ppx) * 96;
            int sw = (ppx & 4) << 2;
            bf16x8 A0 = *(const bf16x8*)(&lds[bofs + ((lk * 16) ^ sw)]);
            bf16x4 A1 = *(const bf16x4*)(&lds[bofs + ((64 + lk * 8) ^ sw)]);
            acc[q] = __builtin_amdgcn_mfma_f32_16x16x32_bf16(A0, Bc8, acc[q], 0, 0, 0);
            acc[q] = mfma_k16(A1, Bc4, acc[q]);
        }
        Bc8 = Bn8; Bc4 = Bn4;
    }

    if (lm < 3) {
#pragma unroll
        for (int q = 0; q < 2; ++q)
#pragma unroll
            for (int rg = 0; rg < 4; ++rg) {
                int pe = (wv * 2 + q) * 16 + lk * 4 + rg;
                int r = pe >> 6, x = pe & 63;
                bounce[(lm * 2 + r) * 64 + x] = acc[q][rg];
            }
    }
    __syncthreads();

    for (int u = threadIdx.x; u < 384; u += 256) {
        int c = u >> 7, r = (u >> 6) & 1, x = u & 63;
        outp[(long)s * 49152 + (long)c * 16384 + (long)(rowb * 2 + r) * 128 + colb * 64 + x] =
            bounce[(c * 2 + r) * 64 + x];
    }
}

// ---------------------------------------------------------------------------
extern "C" void kernel_launch(void* const* d_in, const int* in_sizes, int n_in,
                              void* d_out, int out_size, void* d_ws, size_t ws_size,
                              hipStream_t stream)
{
    const float* inputs  = (const float*)d_in[0];
    const float* cls_w   = (const float*)d_in[1];
    const float* cls_b   = (const float*)d_in[2];
    const float* centers = (const float*)d_in[3];
    const float* head_w  = (const float*)d_in[4];
    const float* head_b  = (const float*)d_in[5];
    const float* bw1     = (const float*)d_in[6];
    const float* bb1     = (const float*)d_in[7];
    const float* bw2     = (const float*)d_in[8];
    const float* bb2     = (const float*)d_in[9];
    const float* body_w  = (const float*)d_in[10];
    const float* body_b  = (const float*)d_in[11];
    const float* up1_w   = (const float*)d_in[12];
    const float* up1_b   = (const float*)d_in[13];
    const float* up2_w   = (const float*)d_in[14];
    const float* up2_b   = (const float*)d_in[15];
    const float* tail_w  = (const float*)d_in[16];
    const float* tail_b  = (const float*)d_in[17];
    float* out = (float*)d_out;

    char* base = (char*)d_ws;
    size_t o = 0;
    auto A = [&](size_t bytes) { size_t r = o; o = (o + bytes + 255) & ~(size_t)255; return r; };

    size_t feat_o  = A(128 * 512 * 4);
    size_t asg_o   = A(512);

    const size_t HEAD_W = (size_t)10 * 9 * 48 * 64;
    const size_t BW_W   = (size_t)80 * 9 * 48 * 64;
    const size_t BODY_W = (size_t)10 * 9 * 48 * 64;
    const size_t UP_W   = (size_t)10 * 9 * 48 * 64;
    const size_t TAIL_W = (size_t)10 * 9 * 16 * 64;

    size_t headw_o = A(HEAD_W * 2);
    size_t bw1_o   = A(BW_W * 2);
    size_t bw2_o   = A(BW_W * 2);
    size_t bodyw_o = A(BODY_W * 2);
    size_t up1w_o  = A(4 * UP_W * 2);
    size_t up2w_o  = A(4 * UP_W * 2);
    size_t tailw_o = A(TAIL_W * 2);

    size_t headb_o = A(10 * 48 * 4);
    size_t bw1b_o  = A(80 * 48 * 4);
    size_t bw2b_o  = A(80 * 48 * 4);
    size_t bodyb_o = A(10 * 48 * 4);
    size_t up1b_o  = A(4 * 10 * 48 * 4);
    size_t up2b_o  = A(4 * 10 * 48 * 4);
    size_t tailb_o = A(10 * 16 * 4);

    size_t fixed_end = o;

    const size_t P32 = (size_t)34 * 34 * 48;
    const size_t PU1 = (size_t)66 * 66 * 48;
    const size_t PU2 = (size_t)130 * 130 * 48;

    // S = trunk chunk samples; SU = up2+tail sub-chunk samples (U2 sized SU)
    int S = 1, SU = 1;
    {
        bool ok = false;
        for (int s_ = NSAMP; s_ >= 1 && !ok; s_ >>= 1)
            for (int su_ = s_; su_ >= 1; su_ >>= 1) {
                size_t need = fixed_end + (size_t)s_ * (4 * P32 + PU1) * 2
                            + (size_t)su_ * PU2 * 2;
                if (need <= ws_size) { S = s_; SU = su_; ok = true; break; }
            }
    }

    short* inclB = (short*)(base + o);
    short* bB = inclB + (size_t)S * P32;
    short* tB = bB + (size_t)S * P32;
    short* hB = tB + (size_t)S * P32;
    short* U1 = hB + (size_t)S * P32;
    short* U2 = U1 + (size_t)S * PU1;

    float* feat   = (float*)(base + feat_o);
    int*   assign = (int*)(base + asg_o);
    short* wbase  = (short*)(base + headw_o);
    float* bbase  = (float*)(base + headb_o);

    short* headwt = (short*)(base + headw_o);
    short* bw1wt  = (short*)(base + bw1_o);
    short* bw2wt  = (short*)(base + bw2_o);
    short* bodywt = (short*)(base + bodyw_o);
    short* up1wt  = (short*)(base + up1w_o);
    short* up2wt  = (short*)(base + up2w_o);
    short* tailwt = (short*)(base + tailw_o);
    float* headbb = (float*)(base + headb_o);
    float* bw1bb  = (float*)(base + bw1b_o);
    float* bw2bb  = (float*)(base + bw2b_o);
    float* bodybb = (float*)(base + bodyb_o);
    float* up1bb  = (float*)(base + up1b_o);
    float* up2bb  = (float*)(base + up2b_o);
    float* tailbb = (float*)(base + tailb_o);

    PrepTable T;
    auto setd = [&](int i, const float* ws_, const float* bs_, int nm, int cop,
                    int cosrc, int coreal, int cireal, int grp,
                    size_t wdo, size_t bdo) {
        T.d[i].wsrc = ws_; T.d[i].bsrc = bs_;
        T.d[i].n_mat = nm; T.d[i].CO_pad = cop; T.d[i].CO_src = cosrc;
        T.d[i].CO_real = coreal; T.d[i].CI_real = cireal; T.d[i].group = grp;
        T.d[i].sz_w = (size_t)nm * 9 * cop * 64;
        T.d[i].sz_b = (size_t)nm * cop;
        T.d[i].wdst = (wdo - headw_o) / 2;
        T.d[i].bdst = (bdo - headb_o) / 4;
    };
    setd(0,  head_w, head_b, 10, 48, 36, 36, 3,  -1, headw_o, headb_o);
    setd(1,  bw1,    bb1,    80, 48, 36, 36, 36, -1, bw1_o,   bw1b_o);
    setd(2,  bw2,    bb2,    80, 48, 36, 36, 36, -1, bw2_o,   bw2b_o);
    setd(3,  body_w, body_b, 10, 48, 36, 36, 36, -1, bodyw_o, bodyb_o);
    for (int g = 0; g < 4; ++g)
        setd(4 + g, up1_w, up1_b, 10, 48, 144, 36, 36, g,
             up1w_o + (size_t)g * UP_W * 2, up1b_o + (size_t)g * 480 * 4);
    for (int g = 0; g < 4; ++g)
        setd(8 + g, up2_w, up2_b, 10, 48, 144, 36, 36, g,
             up2w_o + (size_t)g * UP_W * 2, up2b_o + (size_t)g * 480 * 4);
    setd(12, tail_w, tail_b, 10, 16, 3, 3, 36, -1, tailw_o, tailb_o);

    size_t wtot = 0, btot = 0;
    for (int i = 0; i < 13; ++i) { wtot += T.d[i].sz_w; btot += T.d[i].sz_b; }

    hipLaunchKernelGGL(k_prep, dim3((unsigned)((wtot + btot + 255) / 256)), dim3(256),
                       0, stream, T, wbase, bbase, wtot, btot);

    // combined halo zeroing (U2 buffer holds SU samples)
    {
        HaloTab H;
        short* ps[5] = { inclB, bB, tB, U1, U2 };
        int    hp[5] = { 34, 34, 34, 66, 130 };
        long   ss[5] = { (long)P32, (long)P32, (long)P32, (long)PU1, (long)PU2 };
        int    ns[5] = { S, S, S, S, SU };
        H.cum[0] = 0;
        for (int i = 0; i < 5; ++i) {
            H.p[i] = ps[i]; H.Hp[i] = hp[i]; H.ss[i] = ss[i];
            H.cum[i + 1] = H.cum[i] + (long)ns[i] * (4 * hp[i] - 4) * 6;
        }
        hipLaunchKernelGGL(k_halo_all, dim3((unsigned)((H.cum[5] + 255) / 256)),
                           dim3(256), 0, stream, H);
    }

    hipLaunchKernelGGL(k_cls2, dim3(NSAMP * 64), dim3(128), 0, stream,
                       inputs, cls_w, cls_b, feat);
    hipLaunchKernelGGL(k_assign, dim3(NSAMP), dim3(64), 0, stream,
                       feat, centers, assign);

    const long WES_RES  = 8L * 9 * 48 * 64;
    const long WES_ONE  = 9L * 48 * 64;
    const long WES_TAIL = 9L * 16 * 64;

    for (int bs = 0; bs < NSAMP; bs += S) {
        hipLaunchKernelGGL(k_incl, dim3((S * 1024 + 255) / 256), dim3(256), 0, stream,
                           inputs, inclB, bs, S);
        // head -> bB and hB (8 rows/block: grid S*4)
        hipLaunchKernelGGL((k_conv_res<2, false>), dim3(S * 4), dim3(256), 0, stream,
                           inclB, (long)P32, headwt, WES_ONE, headbb, 48L,
                           assign, bs, bB, (long)P32, (const short*)nullptr, hB, S);
        // fused residual blocks, ping-pong bB <-> tB (8 rows/block: grid S*4)
        short* pin = bB;
        short* pout = tB;
        for (int i = 0; i < NBLK; ++i) {
            hipLaunchKernelGGL(k_res_fused, dim3(S * 4), dim3(256), 0, stream,
                               pin, pout,
                               bw1wt + (size_t)i * WES_ONE, bw1bb + i * 48,
                               bw2wt + (size_t)i * WES_ONE, bw2bb + i * 48,
                               WES_RES, 8L * 48, assign, bs, S);
            short* tmp = pin; pin = pout; pout = tmp;
        }
        // body + global skip -> tB (pin == bB after even number of blocks)
        hipLaunchKernelGGL((k_conv_res<1, false>), dim3(S * 4), dim3(256), 0, stream,
                           pin, (long)P32, bodywt, WES_ONE, bodybb, 48L,
                           assign, bs, tB, (long)P32, hB, (short*)nullptr, S);
        // up1 merged -> U1
        hipLaunchKernelGGL((k_conv_up<32, 2>), dim3(S * 16), dim3(256), 0, stream,
                           tB, (long)P32, up1wt, (long)UP_W, WES_ONE,
                           up1bb, 480L, 48L, assign, bs, U1, (long)PU1, S);
        // up2 + tail in SU-sized sub-chunks (U2 holds SU samples)
        for (int hb = 0; hb < S; hb += SU) {
            hipLaunchKernelGGL((k_conv_up<64, 1>), dim3(SU * 64), dim3(256), 0, stream,
                               U1 + (size_t)hb * PU1, (long)PU1, up2wt, (long)UP_W, WES_ONE,
                               up2bb, 480L, 48L, assign, bs + hb, U2, (long)PU2, SU);
            hipLaunchKernelGGL(k_conv_tail, dim3(SU * 128), dim3(256), 0, stream,
                               U2, (long)PU2, tailwt, WES_TAIL, tailbb, 16L,
                               assign, bs + hb, out + (size_t)(bs + hb) * 49152, SU);
        }
    }
}